// Round 4
// baseline (266.891 us; speedup 1.0000x reference)
//
#include <hip/hip_runtime.h>
#include <hip/hip_bf16.h>

#define DIMF 128
#define KNBR 32
#define NH 4
#define DH 32
#define RADIUS 0.3f
#define CB 4       // centers per attn block (64 threads/center)
#define TC 4       // centers per topk block
#define CAND 320   // max candidates/center
#define PPB 32     // points per nearest_out block

typedef unsigned long long u64t;

// ================= kernel 1: prep (transposes + pdata + cdata) ==============
// block mapping (256 threads each):
//   [0,16)   Wq transpose tiles   [16,32) Wv   [32,48) Wo
//   [48,112) W1 (512x128 -> 128x512)   [112,176) W2 (128x512 -> 512x128)
//   [176,240) pdata (64 blocks)   [240,256) cdata (16 blocks)
__device__ __forceinline__ void tr_tile(const float* __restrict__ in, float* __restrict__ out,
                                        int R, int C, int bx, int by, int t) {
    __shared__ float tile[32][33];
    int tx = t & 31, ty = t >> 5;  // 32 x 8
    for (int r = ty; r < 32; r += 8) tile[r][tx] = in[(long)(by + r) * C + bx + tx];
    __syncthreads();
    for (int r = ty; r < 32; r += 8) out[(long)(bx + r) * R + by + tx] = tile[tx][r];
}

__global__ __launch_bounds__(256) void prep_kernel(
    const float* __restrict__ xyz, const int* __restrict__ idxc,
    const float* __restrict__ Wq, const float* __restrict__ Wv,
    const float* __restrict__ Wo, const float* __restrict__ W1,
    const float* __restrict__ W2,
    float* __restrict__ WqT, float* __restrict__ WvT, float* __restrict__ WoT,
    float* __restrict__ W1T, float* __restrict__ W2T,
    float4* __restrict__ pdata, float4* __restrict__ cdata, int N, int M) {
    int b = blockIdx.x, t = threadIdx.x;
    if (b < 16) {
        tr_tile(Wq, WqT, 128, 128, (b & 3) * 32, ((b >> 2) & 3) * 32, t);
    } else if (b < 32) {
        int i = b - 16; tr_tile(Wv, WvT, 128, 128, (i & 3) * 32, (i >> 2) * 32, t);
    } else if (b < 48) {
        int i = b - 32; tr_tile(Wo, WoT, 128, 128, (i & 3) * 32, (i >> 2) * 32, t);
    } else if (b < 112) {
        int i = b - 48; tr_tile(W1, W1T, 512, 128, (i & 3) * 32, (i >> 2) * 32, t);
    } else if (b < 176) {
        int i = b - 112; tr_tile(W2, W2T, 128, 512, (i & 15) * 32, (i >> 4) * 32, t);
    } else if (b < 240) {
        int n = (b - 176) * 256 + t;
        if (n < N) {
            float x = xyz[3 * n], y = xyz[3 * n + 1], z = xyz[3 * n + 2];
            pdata[n] = make_float4(x, y, z, (x * x + y * y) + z * z);
        }
    } else {
        int m = (b - 240) * 256 + t;
        if (m < M) {
            int i = idxc[m];
            float x = xyz[3 * i], y = xyz[3 * i + 1], z = xyz[3 * i + 2];
            cdata[m] = make_float4(x, y, z, (x * x + y * y) + z * z);  // same fp order as pdata
        }
    }
}

// ================= kernel 2: radius top-K (unchanged from R3) ===============
__global__ __launch_bounds__(256) void topk_kernel(const float4* __restrict__ pdata,
                                                   const float4* __restrict__ cdata,
                                                   int* __restrict__ nbr, int N) {
    __shared__ u64t cand[TC][CAND];
    __shared__ int cnt[TC];
    int t = threadIdx.x;
    int m0 = blockIdx.x * TC;
    if (t < TC) cnt[t] = 0;
    __syncthreads();
    float nx[TC], ny[TC], nz[TC], cw[TC];
#pragma unroll
    for (int tc = 0; tc < TC; ++tc) {
        float4 c = cdata[m0 + tc];
        nx[tc] = -2.0f * c.x; ny[tc] = -2.0f * c.y; nz[tc] = -2.0f * c.z; cw[tc] = c.w;
    }
    const float R2 = RADIUS * RADIUS;
    for (int n = t; n < N; n += 256) {
        float4 p = pdata[n];
#pragma unroll
        for (int tc = 0; tc < TC; ++tc) {
            float d2 = fmaf(nx[tc], p.x, fmaf(ny[tc], p.y, fmaf(nz[tc], p.z, cw[tc] + p.w)));
            if (d2 < R2) {
                int pos = atomicAdd(&cnt[tc], 1);
                if (pos < CAND)
                    cand[tc][pos] = (((u64t)__float_as_uint(fmaxf(d2, 0.0f))) << 32) | (unsigned)n;
            }
        }
    }
    __syncthreads();
    int w = t >> 6, lane = t & 63;
    int C = cnt[w] < CAND ? cnt[w] : CAND;
    const u64t* vc = cand[w];
    int* out = nbr + (m0 + w) * KNBR;
    if (C <= 64) {
        u64t mykey = (lane < C) ? vc[lane] : ~0ull;
        int rank = 0;
        for (int j = 0; j < C; ++j) rank += (vc[j] < mykey) ? 1 : 0;
        if (lane < C && rank < KNBR) out[rank] = (int)(mykey & 0xffffffffu);
        if (lane >= C && lane < KNBR) out[lane] = -1;
    } else {
        u64t mykey[5];
        int myrank[5];
#pragma unroll
        for (int s = 0; s < 5; ++s) {
            int i = s * 64 + lane;
            mykey[s] = (i < C) ? vc[i] : ~0ull;
            myrank[s] = 0;
        }
        for (int j = 0; j < C; ++j) {
            u64t kj = vc[j];
#pragma unroll
            for (int s = 0; s < 5; ++s) myrank[s] += (kj < mykey[s]) ? 1 : 0;
        }
#pragma unroll
        for (int s = 0; s < 5; ++s) {
            int i = s * 64 + lane;
            if (i < C && myrank[s] < KNBR) out[myrank[s]] = (int)(mykey[s] & 0xffffffffu);
        }
    }
}

// ================= kernel 3: attention + FFN, 4 centers / 256 threads =======
__global__ __launch_bounds__(256) void attn_ffn_kernel(
    const float* __restrict__ feats, const int* __restrict__ idxc,
    const int* __restrict__ nbr,
    const float* __restrict__ WqT, const float* __restrict__ Wk,
    const float* __restrict__ WvT, const float* __restrict__ WoT,
    const float* __restrict__ bo, const float* __restrict__ g1,
    const float* __restrict__ be1, const float* __restrict__ g2,
    const float* __restrict__ be2, const float* __restrict__ W1T,
    const float* __restrict__ b1f, const float* __restrict__ W2T,
    const float* __restrict__ b2f, float* __restrict__ cfin) {
    __shared__ __align__(16) float cf[CB][DIMF];
    __shared__ __align__(16) float cf2[CB][DIMF];
    __shared__ __align__(16) float S1[CB][4 * DIMF];  // qw -> pool -> h1
    __shared__ __align__(16) float S2[CB][DIMF];      // q -> updin
    __shared__ __align__(16) float S3[CB][DIMF];      // wsm -> upd -> ffn
    __shared__ int nbrl[CB][KNBR];

    int t = threadIdx.x;
    int m0 = blockIdx.x * CB;
    int i128 = t & 127;       // output index for 128-wide phases
    int g = t >> 7;           // 0/1 -> center pair {2g, 2g+1}
    int cw4 = t >> 6;         // wave id == center for per-center phases
    int l64 = t & 63;

    // ---- load: center rows + neighbor lists ----
    {
        int ic = idxc[m0 + cw4];
        if (l64 < 32) *(float4*)&cf[cw4][l64 * 4] = *(const float4*)&feats[(long)ic * DIMF + l64 * 4];
        else nbrl[cw4][l64 - 32] = nbr[(m0 + cw4) * KNBR + (l64 - 32)];
    }
    __syncthreads();

    // ---- A: q = Wq @ cf (scaled) -> S2 ----
    {
        float acc[2] = {0.f, 0.f};
        for (int jj = 0; jj < 32; ++jj) {
            float w0 = WqT[(jj * 4 + 0) * DIMF + i128];
            float w1 = WqT[(jj * 4 + 1) * DIMF + i128];
            float w2 = WqT[(jj * 4 + 2) * DIMF + i128];
            float w3 = WqT[(jj * 4 + 3) * DIMF + i128];
#pragma unroll
            for (int cc = 0; cc < 2; ++cc) {
                float4 x = *(const float4*)&cf[2 * g + cc][jj * 4];
                acc[cc] += w0 * x.x + w1 * x.y + w2 * x.z + w3 * x.w;
            }
        }
#pragma unroll
        for (int cc = 0; cc < 2; ++cc) S2[2 * g + cc][i128] = acc[cc] * 0.17677669529663687f;
    }
    __syncthreads();

    // ---- B: qw[c][h][j] = sum_d q[c][h*32+d] * Wk[(h*32+d)*128+j] -> S1 ----
    {
        int j = i128;
#pragma unroll
        for (int hh = 0; hh < 2; ++hh) {
            int h = g * 2 + hh;
            float acc[4] = {0.f, 0.f, 0.f, 0.f};
            for (int d4 = 0; d4 < 8; ++d4) {
                float w0 = Wk[(long)(h * DH + d4 * 4 + 0) * DIMF + j];
                float w1 = Wk[(long)(h * DH + d4 * 4 + 1) * DIMF + j];
                float w2 = Wk[(long)(h * DH + d4 * 4 + 2) * DIMF + j];
                float w3 = Wk[(long)(h * DH + d4 * 4 + 3) * DIMF + j];
#pragma unroll
                for (int c = 0; c < 4; ++c) {
                    float4 qv = *(const float4*)&S2[c][h * DH + d4 * 4];
                    acc[c] += qv.x * w0 + qv.y * w1 + qv.z * w2 + qv.w * w3;
                }
            }
#pragma unroll
            for (int c = 0; c < 4; ++c) S1[c][h * DIMF + j] = acc[c];
        }
    }
    __syncthreads();

    // ---- C: logits + softmax -> S3 (wsm[c][h*32+k]) ----
    {
        int c = cw4, hh = (t >> 5) & 1, k = t & 31;
        int ni = nbrl[c][k];
        const float* nrow = feats + (long)(ni < 0 ? 0 : ni) * DIMF;
        float lg[2] = {0.f, 0.f};
        for (int jj = 0; jj < 32; ++jj) {
            float4 f = *(const float4*)&nrow[jj * 4];
#pragma unroll
            for (int e = 0; e < 2; ++e) {
                float4 qwv = *(const float4*)&S1[c][(hh * 2 + e) * DIMF + jj * 4];
                lg[e] += f.x * qwv.x + f.y * qwv.y + f.z * qwv.z + f.w * qwv.w;
            }
        }
        if (ni < 0) { lg[0] = -1e9f; lg[1] = -1e9f; }
#pragma unroll
        for (int e = 0; e < 2; ++e) {
            float mx = lg[e];
            for (int o = 16; o; o >>= 1) mx = fmaxf(mx, __shfl_xor(mx, o, 32));
            float ex = expf(lg[e] - mx);
            float s = ex;
            for (int o = 16; o; o >>= 1) s += __shfl_xor(s, o, 32);
            S3[c][(hh * 2 + e) * KNBR + k] = ex / s;
        }
    }
    __syncthreads();

    // ---- D: pool[c][h][j] = sum_k wsm * nf -> S1 (qw dead) ----
    {
        int c = cw4, hh = (t >> 5) & 1, j4 = (t & 31) * 4;
        float a0x = 0.f, a0y = 0.f, a0z = 0.f, a0w = 0.f;
        float a1x = 0.f, a1y = 0.f, a1z = 0.f, a1w = 0.f;
        for (int k = 0; k < KNBR; ++k) {
            int ni = nbrl[c][k];
            const float* nrow = feats + (long)(ni < 0 ? 0 : ni) * DIMF;
            float4 f = *(const float4*)&nrow[j4];
            float w0 = S3[c][(hh * 2 + 0) * KNBR + k];
            float w1 = S3[c][(hh * 2 + 1) * KNBR + k];
            a0x += w0 * f.x; a0y += w0 * f.y; a0z += w0 * f.z; a0w += w0 * f.w;
            a1x += w1 * f.x; a1y += w1 * f.y; a1z += w1 * f.z; a1w += w1 * f.w;
        }
        *(float4*)&S1[c][(hh * 2 + 0) * DIMF + j4] = make_float4(a0x, a0y, a0z, a0w);
        *(float4*)&S1[c][(hh * 2 + 1) * DIMF + j4] = make_float4(a1x, a1y, a1z, a1w);
    }
    __syncthreads();

    // ---- E: updin[c][d*4+h] = Wv[i] . pool[c][h(i)] -> S2 (q dead) ----
    {
        int i = i128, h = i >> 5, d = i & 31;
        float acc[2] = {0.f, 0.f};
        for (int jj = 0; jj < 32; ++jj) {
            float w0 = WvT[(jj * 4 + 0) * DIMF + i];
            float w1 = WvT[(jj * 4 + 1) * DIMF + i];
            float w2 = WvT[(jj * 4 + 2) * DIMF + i];
            float w3 = WvT[(jj * 4 + 3) * DIMF + i];
#pragma unroll
            for (int cc = 0; cc < 2; ++cc) {
                float4 pv = *(const float4*)&S1[2 * g + cc][h * DIMF + jj * 4];
                acc[cc] += w0 * pv.x + w1 * pv.y + w2 * pv.z + w3 * pv.w;
            }
        }
#pragma unroll
        for (int cc = 0; cc < 2; ++cc) S2[2 * g + cc][d * NH + h] = acc[cc];
    }
    __syncthreads();

    // ---- F: upd = Wo @ updin + bo -> S3 (wsm dead) ----
    {
        int i = i128;
        float acc[2] = {0.f, 0.f};
        for (int jj = 0; jj < 32; ++jj) {
            float w0 = WoT[(jj * 4 + 0) * DIMF + i];
            float w1 = WoT[(jj * 4 + 1) * DIMF + i];
            float w2 = WoT[(jj * 4 + 2) * DIMF + i];
            float w3 = WoT[(jj * 4 + 3) * DIMF + i];
#pragma unroll
            for (int cc = 0; cc < 2; ++cc) {
                float4 x = *(const float4*)&S2[2 * g + cc][jj * 4];
                acc[cc] += w0 * x.x + w1 * x.y + w2 * x.z + w3 * x.w;
            }
        }
        float b = bo[i];
#pragma unroll
        for (int cc = 0; cc < 2; ++cc) S3[2 * g + cc][i] = acc[cc] + b;
    }
    __syncthreads();

    // ---- G: LN1 + residual -> cf2 (one wave per center, float2/lane) ----
    {
        int c = cw4, i2 = l64 * 2;
        float u0 = S3[c][i2], u1 = S3[c][i2 + 1];
        float s = u0 + u1;
        for (int o = 32; o; o >>= 1) s += __shfl_xor(s, o);
        float mu = s * (1.0f / DIMF);
        float d0 = u0 - mu, d1 = u1 - mu;
        float vs = d0 * d0 + d1 * d1;
        for (int o = 32; o; o >>= 1) vs += __shfl_xor(vs, o);
        float rs = 1.0f / sqrtf(vs * (1.0f / DIMF) + 1e-5f);
        cf2[c][i2] = cf[c][i2] + d0 * rs * g1[i2] + be1[i2];
        cf2[c][i2 + 1] = cf[c][i2 + 1] + d1 * rs * g1[i2 + 1] + be1[i2 + 1];
    }
    __syncthreads();

    // ---- H: FFN1 relu(W1 @ cf2 + b1f) -> S1 (pool dead) ----
    {
        int u0 = i128;
        float acc[4][2];
#pragma unroll
        for (int p = 0; p < 4; ++p) { acc[p][0] = 0.f; acc[p][1] = 0.f; }
        for (int jj = 0; jj < 32; ++jj) {
            float4 x[2];
#pragma unroll
            for (int cc = 0; cc < 2; ++cc) x[cc] = *(const float4*)&cf2[2 * g + cc][jj * 4];
#pragma unroll
            for (int p = 0; p < 4; ++p) {
                int u = u0 + p * DIMF;
                float w0 = W1T[(long)(jj * 4 + 0) * (4 * DIMF) + u];
                float w1 = W1T[(long)(jj * 4 + 1) * (4 * DIMF) + u];
                float w2 = W1T[(long)(jj * 4 + 2) * (4 * DIMF) + u];
                float w3 = W1T[(long)(jj * 4 + 3) * (4 * DIMF) + u];
#pragma unroll
                for (int cc = 0; cc < 2; ++cc)
                    acc[p][cc] += w0 * x[cc].x + w1 * x[cc].y + w2 * x[cc].z + w3 * x[cc].w;
            }
        }
#pragma unroll
        for (int p = 0; p < 4; ++p) {
            float b = b1f[u0 + p * DIMF];
#pragma unroll
            for (int cc = 0; cc < 2; ++cc)
                S1[2 * g + cc][u0 + p * DIMF] = fmaxf(acc[p][cc] + b, 0.f);
        }
    }
    __syncthreads();

    // ---- I: FFN2 (W2 @ h1 + b2f) -> S3 (upd dead) ----
    {
        int i = i128;
        float acc[2] = {0.f, 0.f};
        for (int uu = 0; uu < 128; ++uu) {
            float w0 = W2T[(long)(uu * 4 + 0) * DIMF + i];
            float w1 = W2T[(long)(uu * 4 + 1) * DIMF + i];
            float w2 = W2T[(long)(uu * 4 + 2) * DIMF + i];
            float w3 = W2T[(long)(uu * 4 + 3) * DIMF + i];
#pragma unroll
            for (int cc = 0; cc < 2; ++cc) {
                float4 hh = *(const float4*)&S1[2 * g + cc][uu * 4];
                acc[cc] += w0 * hh.x + w1 * hh.y + w2 * hh.z + w3 * hh.w;
            }
        }
        float b = b2f[i];
#pragma unroll
        for (int cc = 0; cc < 2; ++cc) S3[2 * g + cc][i] = acc[cc] + b;
    }
    __syncthreads();

    // ---- J: LN2 + residual -> cfin ----
    {
        int c = cw4, i2 = l64 * 2;
        float u0 = S3[c][i2], u1 = S3[c][i2 + 1];
        float s = u0 + u1;
        for (int o = 32; o; o >>= 1) s += __shfl_xor(s, o);
        float mu = s * (1.0f / DIMF);
        float d0 = u0 - mu, d1 = u1 - mu;
        float vs = d0 * d0 + d1 * d1;
        for (int o = 32; o; o >>= 1) vs += __shfl_xor(vs, o);
        float rs = 1.0f / sqrtf(vs * (1.0f / DIMF) + 1e-5f);
        float r0 = cf2[c][i2] + d0 * rs * g2[i2] + be2[i2];
        float r1 = cf2[c][i2 + 1] + d1 * rs * g2[i2 + 1] + be2[i2 + 1];
        cfin[(long)(m0 + c) * DIMF + i2] = r0;
        cfin[(long)(m0 + c) * DIMF + i2 + 1] = r1;
    }
}

// ================= kernel 4: fused nearest-center + output ==================
// 32 points/block; 8 lanes per point each scan 512 centers; u64 key combine.
__global__ __launch_bounds__(256) void nearest_out_kernel(
    const float4* __restrict__ pdata, const float4* __restrict__ cdata,
    const float* __restrict__ cfin, const float4* __restrict__ feats4,
    float4* __restrict__ out4, int N, int M) {
    __shared__ float4 cds[1024];
    __shared__ int bestm[PPB];
    int t = threadIdx.x;
    int pt = t >> 3, q = t & 7;
    int n = blockIdx.x * PPB + pt;
    float4 p = pdata[n];
    u64t best = ~0ull;
    for (int c0 = 0; c0 < M; c0 += 1024) {
        __syncthreads();
        for (int i = t; i < 1024; i += 256) cds[i] = cdata[c0 + i];
        __syncthreads();
        int base = q * 128;
#pragma unroll 4
        for (int i = 0; i < 128; ++i) {
            float4 c = cds[base + i];
            float d2 = c.w + p.w - 2.0f * (c.x * p.x + c.y * p.y + c.z * p.z);
            float dist = sqrtf(fmaxf(d2, 1e-12f));  // ref tie semantics
            u64t pk = (((u64t)__float_as_uint(dist)) << 32) | (unsigned)(c0 + base + i);
            if (pk < best) best = pk;
        }
    }
#pragma unroll
    for (int o = 1; o < 8; o <<= 1) {
        u64t ob = __shfl_xor(best, o);
        if (ob < best) best = ob;
    }
    if (q == 0) bestm[pt] = (int)(best & 0xffffffffu);
    __syncthreads();
    // output: 32 points x 32 float4 = 1024 float4, 4 per thread
    const float4* cf4 = (const float4*)cfin;
#pragma unroll
    for (int r = 0; r < 4; ++r) {
        int idx = r * 256 + t;
        int pt2 = idx >> 5, col = idx & 31;
        int n2 = blockIdx.x * PPB + pt2;
        float4 f = feats4[(long)n2 * 32 + col];
        float4 gg = cf4[(long)bestm[pt2] * 32 + col];
        out4[(long)n2 * 32 + col] = make_float4(f.x + gg.x, f.y + gg.y, f.z + gg.z, f.w + gg.w);
    }
}

extern "C" void kernel_launch(void* const* d_in, const int* in_sizes, int n_in,
                              void* d_out, int out_size, void* d_ws, size_t ws_size,
                              hipStream_t stream) {
    const float* xyz = (const float*)d_in[0];
    const float* feats = (const float*)d_in[1];
    const int* idxc = (const int*)d_in[2];
    const float* Wq = (const float*)d_in[3];
    const float* Wk = (const float*)d_in[4];
    const float* Wv = (const float*)d_in[5];
    const float* Wo = (const float*)d_in[6];
    const float* bo = (const float*)d_in[7];
    const float* g1 = (const float*)d_in[8];
    const float* be1 = (const float*)d_in[9];
    const float* g2 = (const float*)d_in[10];
    const float* be2 = (const float*)d_in[11];
    const float* W1 = (const float*)d_in[12];
    const float* b1f = (const float*)d_in[13];
    const float* W2 = (const float*)d_in[14];
    const float* b2f = (const float*)d_in[15];

    int N = in_sizes[0] / 3;
    int M = in_sizes[2];

    char* ws = (char*)d_ws;
    size_t off = 0;
    float4* pdata = (float4*)(ws + off); off += (size_t)N * 16;
    float4* cdata = (float4*)(ws + off); off += (size_t)M * 16;
    int* nbr = (int*)(ws + off); off += (size_t)M * KNBR * 4;
    float* cfin = (float*)(ws + off); off += (size_t)M * DIMF * 4;
    float* WqT = (float*)(ws + off); off += (size_t)DIMF * DIMF * 4;
    float* WvT = (float*)(ws + off); off += (size_t)DIMF * DIMF * 4;
    float* WoT = (float*)(ws + off); off += (size_t)DIMF * DIMF * 4;
    float* W1T = (float*)(ws + off); off += (size_t)4 * DIMF * DIMF * 4;
    float* W2T = (float*)(ws + off); off += (size_t)4 * DIMF * DIMF * 4;
    (void)ws_size; (void)n_in; (void)out_size;

    prep_kernel<<<256, 256, 0, stream>>>(xyz, idxc, Wq, Wv, Wo, W1, W2,
                                         WqT, WvT, WoT, W1T, W2T, pdata, cdata, N, M);
    topk_kernel<<<M / TC, 256, 0, stream>>>(pdata, cdata, nbr, N);
    attn_ffn_kernel<<<M / CB, 256, 0, stream>>>(feats, idxc, nbr, WqT, Wk, WvT, WoT, bo,
                                                g1, be1, g2, be2, W1T, b1f, W2T, b2f, cfin);
    nearest_out_kernel<<<N / PPB, 256, 0, stream>>>(pdata, cdata, cfin, (const float4*)feats,
                                                    (float4*)d_out, N, M);
}

// Round 5
// 226.110 us; speedup vs baseline: 1.1804x; 1.1804x over previous
//
#include <hip/hip_runtime.h>
#include <hip/hip_bf16.h>

#define DIMF 128
#define KNBR 32
#define NH 4
#define DH 32
#define RADIUS 0.3f
#define CB 8       // centers per attn block (R3 proven config)
#define TC 4       // centers per topk block
#define CAND 320   // max candidates/center
#define PPB 32     // points per nearest block

#define TOPK_BLOCKS 1024   // M/TC
#define NEAR_BLOCKS 512    // N/PPB
#define TR_BLOCKS 176      // 16+16+16+64+64
#define FRONT_BLOCKS (TOPK_BLOCKS + NEAR_BLOCKS + TR_BLOCKS)

typedef unsigned long long u64t;

// ================= kernel 1: fused front (topk + nearest-argmin + transposes)
// All three tasks depend only on (xyz, idxc, W*) — fully independent, so they
// share one grid and co-schedule. Point/center (x,y,z,|.|^2) are derived
// inline with the exact same fp order previously used via pdata/cdata.
__device__ __forceinline__ void tr_tile_f(const float* __restrict__ in, float* __restrict__ out,
                                          int R, int C, int bx, int by, int t, char* smem) {
    float(*tile)[33] = (float(*)[33])smem;
    int tx = t & 31, ty = t >> 5;  // 32 x 8
    for (int r = ty; r < 32; r += 8) tile[r][tx] = in[(long)(by + r) * C + bx + tx];
    __syncthreads();
    for (int r = ty; r < 32; r += 8) out[(long)(bx + r) * R + by + tx] = tile[tx][r];
}

__global__ __launch_bounds__(256) void fused_front_kernel(
    const float* __restrict__ xyz, const int* __restrict__ idxc,
    const float* __restrict__ Wq, const float* __restrict__ Wv,
    const float* __restrict__ Wo, const float* __restrict__ W1,
    const float* __restrict__ W2,
    float* __restrict__ WqT, float* __restrict__ WvT, float* __restrict__ WoT,
    float* __restrict__ W1T, float* __restrict__ W2T,
    int* __restrict__ nbr, int* __restrict__ bestm, int N, int M) {
    __shared__ __align__(16) char smem[16896];
    int b = blockIdx.x, t = threadIdx.x;

    if (b < TOPK_BLOCKS) {
        // ---------- radius top-K, 4 centers/block ----------
        u64t(*cand)[CAND] = (u64t(*)[CAND])smem;
        int* cnt = (int*)(smem + TC * CAND * 8);
        int m0 = b * TC;
        if (t < TC) cnt[t] = 0;
        __syncthreads();
        float nx[TC], ny[TC], nz[TC], cw[TC];
#pragma unroll
        for (int tc = 0; tc < TC; ++tc) {
            int ic = idxc[m0 + tc];
            float cx = xyz[3 * ic], cy = xyz[3 * ic + 1], cz = xyz[3 * ic + 2];
            cw[tc] = (cx * cx + cy * cy) + cz * cz;
            nx[tc] = -2.0f * cx; ny[tc] = -2.0f * cy; nz[tc] = -2.0f * cz;
        }
        const float R2 = RADIUS * RADIUS;
        for (int n = t; n < N; n += 256) {
            float x = xyz[3 * n], y = xyz[3 * n + 1], z = xyz[3 * n + 2];
            float pw = (x * x + y * y) + z * z;
#pragma unroll
            for (int tc = 0; tc < TC; ++tc) {
                float d2 = fmaf(nx[tc], x, fmaf(ny[tc], y, fmaf(nz[tc], z, cw[tc] + pw)));
                if (d2 < R2) {
                    int pos = atomicAdd(&cnt[tc], 1);
                    if (pos < CAND)
                        cand[tc][pos] = (((u64t)__float_as_uint(fmaxf(d2, 0.0f))) << 32) | (unsigned)n;
                }
            }
        }
        __syncthreads();
        int w = t >> 6, lane = t & 63;
        int C = cnt[w] < CAND ? cnt[w] : CAND;
        const u64t* vc = cand[w];
        int* out = nbr + (m0 + w) * KNBR;
        if (C <= 64) {
            u64t mykey = (lane < C) ? vc[lane] : ~0ull;
            int rank = 0;
            for (int j = 0; j < C; ++j) rank += (vc[j] < mykey) ? 1 : 0;
            if (lane < C && rank < KNBR) out[rank] = (int)(mykey & 0xffffffffu);
            if (lane >= C && lane < KNBR) out[lane] = -1;
        } else {
            u64t mykey[5];
            int myrank[5];
#pragma unroll
            for (int s = 0; s < 5; ++s) {
                int i = s * 64 + lane;
                mykey[s] = (i < C) ? vc[i] : ~0ull;
                myrank[s] = 0;
            }
            for (int j = 0; j < C; ++j) {
                u64t kj = vc[j];
#pragma unroll
                for (int s = 0; s < 5; ++s) myrank[s] += (kj < mykey[s]) ? 1 : 0;
            }
#pragma unroll
            for (int s = 0; s < 5; ++s) {
                int i = s * 64 + lane;
                if (i < C && myrank[s] < KNBR) out[myrank[s]] = (int)(mykey[s] & 0xffffffffu);
            }
        }
    } else if (b < TOPK_BLOCKS + NEAR_BLOCKS) {
        // ---------- nearest-center argmin, 32 points/block, 8 lanes/point ----
        float4* cds = (float4*)smem;
        int nb = b - TOPK_BLOCKS;
        int pt = t >> 3, q = t & 7;
        int n = nb * PPB + pt;
        float px = xyz[3 * n], py = xyz[3 * n + 1], pz = xyz[3 * n + 2];
        float pw = (px * px + py * py) + pz * pz;
        u64t best = ~0ull;
        for (int c0 = 0; c0 < M; c0 += 1024) {
            __syncthreads();
            for (int i = t; i < 1024; i += 256) {
                int ic = idxc[c0 + i];
                float cx = xyz[3 * ic], cy = xyz[3 * ic + 1], cz = xyz[3 * ic + 2];
                cds[i] = make_float4(cx, cy, cz, (cx * cx + cy * cy) + cz * cz);
            }
            __syncthreads();
            int base = q * 128;
#pragma unroll 4
            for (int i = 0; i < 128; ++i) {
                float4 c = cds[base + i];
                float d2 = c.w + pw - 2.0f * (c.x * px + c.y * py + c.z * pz);
                float dist = sqrtf(fmaxf(d2, 1e-12f));  // ref tie semantics (np.argmin on dist)
                u64t pk = (((u64t)__float_as_uint(dist)) << 32) | (unsigned)(c0 + base + i);
                if (pk < best) best = pk;
            }
        }
#pragma unroll
        for (int o = 1; o < 8; o <<= 1) {
            u64t ob = __shfl_xor(best, o);
            if (ob < best) best = ob;
        }
        if (q == 0) bestm[n] = (int)(best & 0xffffffffu);
    } else {
        // ---------- weight transposes ----------
        int i = b - (TOPK_BLOCKS + NEAR_BLOCKS);
        if (i < 16) tr_tile_f(Wq, WqT, 128, 128, (i & 3) * 32, (i >> 2) * 32, t, smem);
        else if (i < 32) { i -= 16; tr_tile_f(Wv, WvT, 128, 128, (i & 3) * 32, (i >> 2) * 32, t, smem); }
        else if (i < 48) { i -= 32; tr_tile_f(Wo, WoT, 128, 128, (i & 3) * 32, (i >> 2) * 32, t, smem); }
        else if (i < 112) { i -= 48; tr_tile_f(W1, W1T, 512, 128, (i & 3) * 32, (i >> 2) * 32, t, smem); }
        else { i -= 112; tr_tile_f(W2, W2T, 128, 512, (i & 15) * 32, (i >> 4) * 32, t, smem); }
    }
}

// ================= kernel 2: attention + FFN, 8 centers / 256 threads =======
// Exact R3 structure (CB=8, 4 accumulators/thread) — measured 67 µs.
__global__ __launch_bounds__(256) void attn_ffn_kernel(
    const float* __restrict__ feats, const int* __restrict__ idxc,
    const int* __restrict__ nbr,
    const float* __restrict__ WqT, const float* __restrict__ Wk,
    const float* __restrict__ WvT, const float* __restrict__ WoT,
    const float* __restrict__ bo, const float* __restrict__ g1,
    const float* __restrict__ be1, const float* __restrict__ g2,
    const float* __restrict__ be2, const float* __restrict__ W1T,
    const float* __restrict__ b1f, const float* __restrict__ W2T,
    const float* __restrict__ b2f, float* __restrict__ cfin) {
    __shared__ __align__(16) float cf[CB][DIMF];
    __shared__ __align__(16) float cf2[CB][DIMF];
    __shared__ __align__(16) float S1[CB][4 * DIMF];  // qw -> pool -> h1
    __shared__ __align__(16) float S2[CB][DIMF];      // q -> updin
    __shared__ __align__(16) float S3[CB][DIMF];      // wsm -> upd -> ffn
    __shared__ int nbrl[CB][KNBR];

    int t = threadIdx.x;
    int m0 = blockIdx.x * CB;
    int lane127 = t & 127;
    int cg = (t >> 7) * 4;  // wave-uniform center group {0..3} or {4..7}
    int c8 = t >> 5, k32 = t & 31;

    {
        int ic = idxc[m0 + c8];
        *(float4*)&cf[c8][k32 * 4] = *(const float4*)&feats[(long)ic * DIMF + k32 * 4];
        nbrl[c8][k32] = nbr[(m0 + c8) * KNBR + k32];
    }
    __syncthreads();

    // ---- A: q = Wq @ cf (scaled) -> S2 ----
    {
        float acc[4] = {0.f, 0.f, 0.f, 0.f};
        for (int jj = 0; jj < 32; ++jj) {
            float w0 = WqT[(jj * 4 + 0) * DIMF + lane127];
            float w1 = WqT[(jj * 4 + 1) * DIMF + lane127];
            float w2 = WqT[(jj * 4 + 2) * DIMF + lane127];
            float w3 = WqT[(jj * 4 + 3) * DIMF + lane127];
#pragma unroll
            for (int cc = 0; cc < 4; ++cc) {
                float4 x = *(const float4*)&cf[cg + cc][jj * 4];
                acc[cc] += w0 * x.x + w1 * x.y + w2 * x.z + w3 * x.w;
            }
        }
#pragma unroll
        for (int cc = 0; cc < 4; ++cc) S2[cg + cc][lane127] = acc[cc] * 0.17677669529663687f;
    }
    __syncthreads();

    // ---- B: qw[c][h][j] = sum_d q[c][h*32+d] * Wk[(h*32+d)*128+j] -> S1 ----
    {
        int j = lane127, hs = t >> 7;
#pragma unroll
        for (int hh = 0; hh < 2; ++hh) {
            int h = hs * 2 + hh;
            float acc[8] = {0.f, 0.f, 0.f, 0.f, 0.f, 0.f, 0.f, 0.f};
            for (int d4 = 0; d4 < 8; ++d4) {
                float w0 = Wk[(long)(h * DH + d4 * 4 + 0) * DIMF + j];
                float w1 = Wk[(long)(h * DH + d4 * 4 + 1) * DIMF + j];
                float w2 = Wk[(long)(h * DH + d4 * 4 + 2) * DIMF + j];
                float w3 = Wk[(long)(h * DH + d4 * 4 + 3) * DIMF + j];
#pragma unroll
                for (int c = 0; c < 8; ++c) {
                    float4 qv = *(const float4*)&S2[c][h * DH + d4 * 4];
                    acc[c] += qv.x * w0 + qv.y * w1 + qv.z * w2 + qv.w * w3;
                }
            }
#pragma unroll
            for (int c = 0; c < 8; ++c) S1[c][h * DIMF + j] = acc[c];
        }
    }
    __syncthreads();

    // ---- C: logits + softmax -> S3 (wsm[c][h*32+k]) ----
    {
        int ni = nbrl[c8][k32];
        const float* nrow = feats + (long)(ni < 0 ? 0 : ni) * DIMF;
        float lg[4] = {0.f, 0.f, 0.f, 0.f};
        for (int jj = 0; jj < 32; ++jj) {
            float4 f = *(const float4*)&nrow[jj * 4];
#pragma unroll
            for (int h = 0; h < 4; ++h) {
                float4 qwv = *(const float4*)&S1[c8][h * DIMF + jj * 4];
                lg[h] += f.x * qwv.x + f.y * qwv.y + f.z * qwv.z + f.w * qwv.w;
            }
        }
        if (ni < 0) { lg[0] = -1e9f; lg[1] = -1e9f; lg[2] = -1e9f; lg[3] = -1e9f; }
#pragma unroll
        for (int h = 0; h < 4; ++h) {
            float mx = lg[h];
            for (int o = 16; o; o >>= 1) mx = fmaxf(mx, __shfl_xor(mx, o, 32));
            float e = expf(lg[h] - mx);
            float s = e;
            for (int o = 16; o; o >>= 1) s += __shfl_xor(s, o, 32);
            S3[c8][h * KNBR + k32] = e / s;
        }
    }
    __syncthreads();

    // ---- D: pool[c][h][j] = sum_k wsm * nf -> S1 (overwrite qw) ----
    {
        int j4 = k32 * 4;
        float a0x = 0.f, a0y = 0.f, a0z = 0.f, a0w = 0.f;
        float a1x = 0.f, a1y = 0.f, a1z = 0.f, a1w = 0.f;
        float a2x = 0.f, a2y = 0.f, a2z = 0.f, a2w = 0.f;
        float a3x = 0.f, a3y = 0.f, a3z = 0.f, a3w = 0.f;
        for (int k = 0; k < KNBR; ++k) {
            int ni = nbrl[c8][k];
            const float* nrow = feats + (long)(ni < 0 ? 0 : ni) * DIMF;
            float4 f = *(const float4*)&nrow[j4];
            float w0 = S3[c8][0 * KNBR + k], w1 = S3[c8][1 * KNBR + k];
            float w2 = S3[c8][2 * KNBR + k], w3 = S3[c8][3 * KNBR + k];
            a0x += w0 * f.x; a0y += w0 * f.y; a0z += w0 * f.z; a0w += w0 * f.w;
            a1x += w1 * f.x; a1y += w1 * f.y; a1z += w1 * f.z; a1w += w1 * f.w;
            a2x += w2 * f.x; a2y += w2 * f.y; a2z += w2 * f.z; a2w += w2 * f.w;
            a3x += w3 * f.x; a3y += w3 * f.y; a3z += w3 * f.z; a3w += w3 * f.w;
        }
        __syncthreads();
        *(float4*)&S1[c8][0 * DIMF + j4] = make_float4(a0x, a0y, a0z, a0w);
        *(float4*)&S1[c8][1 * DIMF + j4] = make_float4(a1x, a1y, a1z, a1w);
        *(float4*)&S1[c8][2 * DIMF + j4] = make_float4(a2x, a2y, a2z, a2w);
        *(float4*)&S1[c8][3 * DIMF + j4] = make_float4(a3x, a3y, a3z, a3w);
    }
    __syncthreads();

    // ---- E: updin[c][i->d*4+h] = Wv[i] . pool[c][h(i)] -> S2 ----
    {
        int i = lane127, h = i >> 5, d = i & 31;
        float acc[4] = {0.f, 0.f, 0.f, 0.f};
        for (int jj = 0; jj < 32; ++jj) {
            float w0 = WvT[(jj * 4 + 0) * DIMF + i];
            float w1 = WvT[(jj * 4 + 1) * DIMF + i];
            float w2 = WvT[(jj * 4 + 2) * DIMF + i];
            float w3 = WvT[(jj * 4 + 3) * DIMF + i];
#pragma unroll
            for (int cc = 0; cc < 4; ++cc) {
                float4 pv = *(const float4*)&S1[cg + cc][h * DIMF + jj * 4];
                acc[cc] += w0 * pv.x + w1 * pv.y + w2 * pv.z + w3 * pv.w;
            }
        }
        __syncthreads();
#pragma unroll
        for (int cc = 0; cc < 4; ++cc) S2[cg + cc][d * NH + h] = acc[cc];
    }
    __syncthreads();

    // ---- F: upd = Wo @ updin + bo -> S3 ----
    {
        int i = lane127;
        float acc[4] = {0.f, 0.f, 0.f, 0.f};
        for (int jj = 0; jj < 32; ++jj) {
            float w0 = WoT[(jj * 4 + 0) * DIMF + i];
            float w1 = WoT[(jj * 4 + 1) * DIMF + i];
            float w2 = WoT[(jj * 4 + 2) * DIMF + i];
            float w3 = WoT[(jj * 4 + 3) * DIMF + i];
#pragma unroll
            for (int cc = 0; cc < 4; ++cc) {
                float4 x = *(const float4*)&S2[cg + cc][jj * 4];
                acc[cc] += w0 * x.x + w1 * x.y + w2 * x.z + w3 * x.w;
            }
        }
        float b = bo[i];
        __syncthreads();
#pragma unroll
        for (int cc = 0; cc < 4; ++cc) S3[cg + cc][i] = acc[cc] + b;
    }
    __syncthreads();

    // ---- G: LN1 + residual -> cf2 ----
    {
        int i4 = k32 * 4;
        float4 u = *(const float4*)&S3[c8][i4];
        float s = ((u.x + u.y) + u.z) + u.w;
        for (int o = 16; o; o >>= 1) s += __shfl_xor(s, o, 32);
        float mu = s * (1.0f / DIMF);
        float d0 = u.x - mu, d1 = u.y - mu, d2 = u.z - mu, d3 = u.w - mu;
        float vs = ((d0 * d0 + d1 * d1) + d2 * d2) + d3 * d3;
        for (int o = 16; o; o >>= 1) vs += __shfl_xor(vs, o, 32);
        float rs = 1.0f / sqrtf(vs * (1.0f / DIMF) + 1e-5f);
        float4 g = *(const float4*)&g1[i4];
        float4 b = *(const float4*)&be1[i4];
        float4 base = *(const float4*)&cf[c8][i4];
        float4 r;
        r.x = base.x + d0 * rs * g.x + b.x;
        r.y = base.y + d1 * rs * g.y + b.y;
        r.z = base.z + d2 * rs * g.z + b.z;
        r.w = base.w + d3 * rs * g.w + b.w;
        *(float4*)&cf2[c8][i4] = r;
    }
    __syncthreads();

    // ---- H: FFN1 (relu(W1 @ cf2 + b1f)) -> S1 ----
    {
        int u0 = lane127;
        float acc[4][4];
#pragma unroll
        for (int p = 0; p < 4; ++p)
#pragma unroll
            for (int cc = 0; cc < 4; ++cc) acc[p][cc] = 0.f;
        for (int jj = 0; jj < 32; ++jj) {
            float4 x[4];
#pragma unroll
            for (int cc = 0; cc < 4; ++cc) x[cc] = *(const float4*)&cf2[cg + cc][jj * 4];
#pragma unroll
            for (int p = 0; p < 4; ++p) {
                int u = u0 + p * DIMF;
                float w0 = W1T[(long)(jj * 4 + 0) * (4 * DIMF) + u];
                float w1 = W1T[(long)(jj * 4 + 1) * (4 * DIMF) + u];
                float w2 = W1T[(long)(jj * 4 + 2) * (4 * DIMF) + u];
                float w3 = W1T[(long)(jj * 4 + 3) * (4 * DIMF) + u];
#pragma unroll
                for (int cc = 0; cc < 4; ++cc)
                    acc[p][cc] += w0 * x[cc].x + w1 * x[cc].y + w2 * x[cc].z + w3 * x[cc].w;
            }
        }
#pragma unroll
        for (int p = 0; p < 4; ++p) {
            float b = b1f[u0 + p * DIMF];
#pragma unroll
            for (int cc = 0; cc < 4; ++cc)
                S1[cg + cc][u0 + p * DIMF] = fmaxf(acc[p][cc] + b, 0.f);
        }
    }
    __syncthreads();

    // ---- I: FFN2 (W2 @ h1 + b2f) -> S3 ----
    {
        int i = lane127;
        float acc[4] = {0.f, 0.f, 0.f, 0.f};
        for (int uu = 0; uu < 128; ++uu) {
            float w0 = W2T[(long)(uu * 4 + 0) * DIMF + i];
            float w1 = W2T[(long)(uu * 4 + 1) * DIMF + i];
            float w2 = W2T[(long)(uu * 4 + 2) * DIMF + i];
            float w3 = W2T[(long)(uu * 4 + 3) * DIMF + i];
#pragma unroll
            for (int cc = 0; cc < 4; ++cc) {
                float4 hh = *(const float4*)&S1[cg + cc][uu * 4];
                acc[cc] += w0 * hh.x + w1 * hh.y + w2 * hh.z + w3 * hh.w;
            }
        }
        float b = b2f[i];
        __syncthreads();
#pragma unroll
        for (int cc = 0; cc < 4; ++cc) S3[cg + cc][i] = acc[cc] + b;
    }
    __syncthreads();

    // ---- J: LN2 + residual -> cfin ----
    {
        int i4 = k32 * 4;
        float4 u = *(const float4*)&S3[c8][i4];
        float s = ((u.x + u.y) + u.z) + u.w;
        for (int o = 16; o; o >>= 1) s += __shfl_xor(s, o, 32);
        float mu = s * (1.0f / DIMF);
        float d0 = u.x - mu, d1 = u.y - mu, d2 = u.z - mu, d3 = u.w - mu;
        float vs = ((d0 * d0 + d1 * d1) + d2 * d2) + d3 * d3;
        for (int o = 16; o; o >>= 1) vs += __shfl_xor(vs, o, 32);
        float rs = 1.0f / sqrtf(vs * (1.0f / DIMF) + 1e-5f);
        float4 g = *(const float4*)&g2[i4];
        float4 b = *(const float4*)&be2[i4];
        float4 base = *(const float4*)&cf2[c8][i4];
        float4 r;
        r.x = base.x + d0 * rs * g.x + b.x;
        r.y = base.y + d1 * rs * g.y + b.y;
        r.z = base.z + d2 * rs * g.z + b.z;
        r.w = base.w + d3 * rs * g.w + b.w;
        *(float4*)&cfin[(long)(m0 + c8) * DIMF + i4] = r;
    }
}

// ================= kernel 3: out = feats + cfin[bestm] ======================
__global__ __launch_bounds__(256) void out_kernel(const float4* __restrict__ feats4,
                                                  const float* __restrict__ cfin,
                                                  const int* __restrict__ bestm,
                                                  float4* __restrict__ out4, int total) {
    int idx = blockIdx.x * 256 + threadIdx.x;
    if (idx >= total) return;
    int n = idx >> 5, c = idx & 31;
    const float4* cf4 = (const float4*)cfin;
    float4 f = feats4[idx];
    float4 g = cf4[(long)bestm[n] * 32 + c];
    out4[idx] = make_float4(f.x + g.x, f.y + g.y, f.z + g.z, f.w + g.w);
}

extern "C" void kernel_launch(void* const* d_in, const int* in_sizes, int n_in,
                              void* d_out, int out_size, void* d_ws, size_t ws_size,
                              hipStream_t stream) {
    const float* xyz = (const float*)d_in[0];
    const float* feats = (const float*)d_in[1];
    const int* idxc = (const int*)d_in[2];
    const float* Wq = (const float*)d_in[3];
    const float* Wk = (const float*)d_in[4];
    const float* Wv = (const float*)d_in[5];
    const float* Wo = (const float*)d_in[6];
    const float* bo = (const float*)d_in[7];
    const float* g1 = (const float*)d_in[8];
    const float* be1 = (const float*)d_in[9];
    const float* g2 = (const float*)d_in[10];
    const float* be2 = (const float*)d_in[11];
    const float* W1 = (const float*)d_in[12];
    const float* b1f = (const float*)d_in[13];
    const float* W2 = (const float*)d_in[14];
    const float* b2f = (const float*)d_in[15];

    int N = in_sizes[0] / 3;
    int M = in_sizes[2];

    char* ws = (char*)d_ws;
    size_t off = 0;
    int* nbr = (int*)(ws + off); off += (size_t)M * KNBR * 4;
    float* cfin = (float*)(ws + off); off += (size_t)M * DIMF * 4;
    int* bestm = (int*)(ws + off); off += (size_t)N * 4;
    float* WqT = (float*)(ws + off); off += (size_t)DIMF * DIMF * 4;
    float* WvT = (float*)(ws + off); off += (size_t)DIMF * DIMF * 4;
    float* WoT = (float*)(ws + off); off += (size_t)DIMF * DIMF * 4;
    float* W1T = (float*)(ws + off); off += (size_t)4 * DIMF * DIMF * 4;
    float* W2T = (float*)(ws + off); off += (size_t)4 * DIMF * DIMF * 4;
    (void)ws_size; (void)n_in; (void)out_size;

    fused_front_kernel<<<FRONT_BLOCKS, 256, 0, stream>>>(
        xyz, idxc, Wq, Wv, Wo, W1, W2, WqT, WvT, WoT, W1T, W2T, nbr, bestm, N, M);
    attn_ffn_kernel<<<M / CB, 256, 0, stream>>>(feats, idxc, nbr, WqT, Wk, WvT, WoT, bo,
                                                g1, be1, g2, be2, W1T, b1f, W2T, b2f, cfin);
    out_kernel<<<(N * DIMF / 4 + 255) / 256, 256, 0, stream>>>(
        (const float4*)feats, cfin, bestm, (float4*)d_out, N * DIMF / 4);
}

// Round 6
// 224.005 us; speedup vs baseline: 1.1915x; 1.0094x over previous
//
#include <hip/hip_runtime.h>
#include <hip/hip_bf16.h>

#define DIMF 128
#define KNBR 32
#define NH 4
#define DH 32
#define RADIUS 0.3f
#define CB 8       // centers per attn block (R3 proven config)
#define TC 4       // centers per topk block
#define CAND 320   // max candidates/center
#define PPB 32     // points per nearest block

#define TOPK_BLOCKS 1024   // M/TC
#define NEAR_BLOCKS 512    // N/PPB
#define TR_BLOCKS 176      // 16+16+16+64+64
#define FRONT_BLOCKS (TOPK_BLOCKS + NEAR_BLOCKS + TR_BLOCKS)

typedef unsigned long long u64t;

// ================= kernel 1: fused front (topk + nearest-argmin + transposes)
__device__ __forceinline__ void tr_tile_f(const float* __restrict__ in, float* __restrict__ out,
                                          int R, int C, int bx, int by, int t, char* smem) {
    float(*tile)[33] = (float(*)[33])smem;
    int tx = t & 31, ty = t >> 5;  // 32 x 8
    for (int r = ty; r < 32; r += 8) tile[r][tx] = in[(long)(by + r) * C + bx + tx];
    __syncthreads();
    for (int r = ty; r < 32; r += 8) out[(long)(bx + r) * R + by + tx] = tile[tx][r];
}

__global__ __launch_bounds__(256) void fused_front_kernel(
    const float* __restrict__ xyz, const int* __restrict__ idxc,
    const float* __restrict__ Wq, const float* __restrict__ Wv,
    const float* __restrict__ Wo, const float* __restrict__ W1,
    const float* __restrict__ W2,
    float* __restrict__ WqT, float* __restrict__ WvT, float* __restrict__ WoT,
    float* __restrict__ W1T, float* __restrict__ W2T,
    int* __restrict__ nbr, int* __restrict__ bestm, int N, int M) {
    __shared__ __align__(16) char smem[16896];
    int b = blockIdx.x, t = threadIdx.x;

    if (b < TOPK_BLOCKS) {
        // ---------- radius top-K, 4 centers/block ----------
        u64t(*cand)[CAND] = (u64t(*)[CAND])smem;
        int* cnt = (int*)(smem + TC * CAND * 8);
        int m0 = b * TC;
        if (t < TC) cnt[t] = 0;
        __syncthreads();
        float nx[TC], ny[TC], nz[TC], cw[TC];
#pragma unroll
        for (int tc = 0; tc < TC; ++tc) {
            int ic = idxc[m0 + tc];
            float cx = xyz[3 * ic], cy = xyz[3 * ic + 1], cz = xyz[3 * ic + 2];
            cw[tc] = (cx * cx + cy * cy) + cz * cz;
            nx[tc] = -2.0f * cx; ny[tc] = -2.0f * cy; nz[tc] = -2.0f * cz;
        }
        const float R2 = RADIUS * RADIUS;
        for (int n = t; n < N; n += 256) {
            float x = xyz[3 * n], y = xyz[3 * n + 1], z = xyz[3 * n + 2];
            float pw = (x * x + y * y) + z * z;
#pragma unroll
            for (int tc = 0; tc < TC; ++tc) {
                float d2 = fmaf(nx[tc], x, fmaf(ny[tc], y, fmaf(nz[tc], z, cw[tc] + pw)));
                if (d2 < R2) {
                    int pos = atomicAdd(&cnt[tc], 1);
                    if (pos < CAND)
                        cand[tc][pos] = (((u64t)__float_as_uint(fmaxf(d2, 0.0f))) << 32) | (unsigned)n;
                }
            }
        }
        __syncthreads();
        int w = t >> 6, lane = t & 63;
        int C = cnt[w] < CAND ? cnt[w] : CAND;
        const u64t* vc = cand[w];
        int* out = nbr + (m0 + w) * KNBR;
        if (C <= 64) {
            u64t mykey = (lane < C) ? vc[lane] : ~0ull;
            int rank = 0;
            for (int j = 0; j < C; ++j) rank += (vc[j] < mykey) ? 1 : 0;
            if (lane < C && rank < KNBR) out[rank] = (int)(mykey & 0xffffffffu);
            if (lane >= C && lane < KNBR) out[lane] = -1;
        } else {
            u64t mykey[5];
            int myrank[5];
#pragma unroll
            for (int s = 0; s < 5; ++s) {
                int i = s * 64 + lane;
                mykey[s] = (i < C) ? vc[i] : ~0ull;
                myrank[s] = 0;
            }
            for (int j = 0; j < C; ++j) {
                u64t kj = vc[j];
#pragma unroll
                for (int s = 0; s < 5; ++s) myrank[s] += (kj < mykey[s]) ? 1 : 0;
            }
#pragma unroll
            for (int s = 0; s < 5; ++s) {
                int i = s * 64 + lane;
                if (i < C && myrank[s] < KNBR) out[myrank[s]] = (int)(mykey[s] & 0xffffffffu);
            }
        }
    } else if (b < TOPK_BLOCKS + NEAR_BLOCKS) {
        // ---------- nearest-center argmin, 32 points/block, 8 lanes/point ----
        // Lane q scans centers q, q+8, q+16, ... (stride-8 interleave): the 8
        // active address streams in a wave hit disjoint bank quads (4q..4q+3),
        // pt-lanes broadcast -> conflict-free (was 8-way conflict at q*128+i).
        float4* cds = (float4*)smem;
        int nb = b - TOPK_BLOCKS;
        int pt = t >> 3, q = t & 7;
        int n = nb * PPB + pt;
        float px = xyz[3 * n], py = xyz[3 * n + 1], pz = xyz[3 * n + 2];
        float pw = (px * px + py * py) + pz * pz;
        u64t best = ~0ull;
        for (int c0 = 0; c0 < M; c0 += 1024) {
            __syncthreads();
            for (int i = t; i < 1024; i += 256) {
                int ic = idxc[c0 + i];
                float cx = xyz[3 * ic], cy = xyz[3 * ic + 1], cz = xyz[3 * ic + 2];
                cds[i] = make_float4(cx, cy, cz, (cx * cx + cy * cy) + cz * cz);
            }
            __syncthreads();
#pragma unroll 4
            for (int i = 0; i < 128; ++i) {
                int ci = q + i * 8;
                float4 c = cds[ci];
                float d2 = c.w + pw - 2.0f * (c.x * px + c.y * py + c.z * pz);
                float dist = sqrtf(fmaxf(d2, 1e-12f));  // ref tie semantics (np.argmin on dist)
                u64t pk = (((u64t)__float_as_uint(dist)) << 32) | (unsigned)(c0 + ci);
                if (pk < best) best = pk;
            }
        }
#pragma unroll
        for (int o = 1; o < 8; o <<= 1) {
            u64t ob = __shfl_xor(best, o);
            if (ob < best) best = ob;
        }
        if (q == 0) bestm[n] = (int)(best & 0xffffffffu);
    } else {
        // ---------- weight transposes ----------
        int i = b - (TOPK_BLOCKS + NEAR_BLOCKS);
        if (i < 16) tr_tile_f(Wq, WqT, 128, 128, (i & 3) * 32, (i >> 2) * 32, t, smem);
        else if (i < 32) { i -= 16; tr_tile_f(Wv, WvT, 128, 128, (i & 3) * 32, (i >> 2) * 32, t, smem); }
        else if (i < 48) { i -= 32; tr_tile_f(Wo, WoT, 128, 128, (i & 3) * 32, (i >> 2) * 32, t, smem); }
        else if (i < 112) { i -= 48; tr_tile_f(W1, W1T, 512, 128, (i & 3) * 32, (i >> 2) * 32, t, smem); }
        else { i -= 112; tr_tile_f(W2, W2T, 128, 512, (i & 15) * 32, (i >> 4) * 32, t, smem); }
    }
}

// ================= kernel 2: attention + FFN, 8 centers / 256 threads =======
__global__ __launch_bounds__(256) void attn_ffn_kernel(
    const float* __restrict__ feats, const int* __restrict__ idxc,
    const int* __restrict__ nbr,
    const float* __restrict__ WqT, const float* __restrict__ Wk,
    const float* __restrict__ WvT, const float* __restrict__ WoT,
    const float* __restrict__ bo, const float* __restrict__ g1,
    const float* __restrict__ be1, const float* __restrict__ g2,
    const float* __restrict__ be2, const float* __restrict__ W1T,
    const float* __restrict__ b1f, const float* __restrict__ W2T,
    const float* __restrict__ b2f, float* __restrict__ cfin) {
    __shared__ __align__(16) float cf[CB][DIMF];
    __shared__ __align__(16) float cf2[CB][DIMF];
    __shared__ __align__(16) float S1[CB][4 * DIMF];  // qw -> pool -> h1
    __shared__ __align__(16) float S2[CB][DIMF];      // q -> updin
    __shared__ __align__(16) float S3[CB][DIMF];      // wsm -> upd -> ffn
    __shared__ int nbrl[CB][KNBR];

    int t = threadIdx.x;
    int m0 = blockIdx.x * CB;
    int lane127 = t & 127;
    int cg = (t >> 7) * 4;  // wave-uniform center group {0..3} or {4..7}
    int c8 = t >> 5, k32 = t & 31;

    {
        int ic = idxc[m0 + c8];
        *(float4*)&cf[c8][k32 * 4] = *(const float4*)&feats[(long)ic * DIMF + k32 * 4];
        nbrl[c8][k32] = nbr[(m0 + c8) * KNBR + k32];
    }
    __syncthreads();

    // ---- A: q = Wq @ cf (scaled) -> S2 ----
    {
        float acc[4] = {0.f, 0.f, 0.f, 0.f};
        for (int jj = 0; jj < 32; ++jj) {
            float w0 = WqT[(jj * 4 + 0) * DIMF + lane127];
            float w1 = WqT[(jj * 4 + 1) * DIMF + lane127];
            float w2 = WqT[(jj * 4 + 2) * DIMF + lane127];
            float w3 = WqT[(jj * 4 + 3) * DIMF + lane127];
#pragma unroll
            for (int cc = 0; cc < 4; ++cc) {
                float4 x = *(const float4*)&cf[cg + cc][jj * 4];
                acc[cc] += w0 * x.x + w1 * x.y + w2 * x.z + w3 * x.w;
            }
        }
#pragma unroll
        for (int cc = 0; cc < 4; ++cc) S2[cg + cc][lane127] = acc[cc] * 0.17677669529663687f;
    }
    __syncthreads();

    // ---- B: qw[c][h][j] = sum_d q[c][h*32+d] * Wk[(h*32+d)*128+j] -> S1 ----
    {
        int j = lane127, hs = t >> 7;
#pragma unroll
        for (int hh = 0; hh < 2; ++hh) {
            int h = hs * 2 + hh;
            float acc[8] = {0.f, 0.f, 0.f, 0.f, 0.f, 0.f, 0.f, 0.f};
            for (int d4 = 0; d4 < 8; ++d4) {
                float w0 = Wk[(long)(h * DH + d4 * 4 + 0) * DIMF + j];
                float w1 = Wk[(long)(h * DH + d4 * 4 + 1) * DIMF + j];
                float w2 = Wk[(long)(h * DH + d4 * 4 + 2) * DIMF + j];
                float w3 = Wk[(long)(h * DH + d4 * 4 + 3) * DIMF + j];
#pragma unroll
                for (int c = 0; c < 8; ++c) {
                    float4 qv = *(const float4*)&S2[c][h * DH + d4 * 4];
                    acc[c] += qv.x * w0 + qv.y * w1 + qv.z * w2 + qv.w * w3;
                }
            }
#pragma unroll
            for (int c = 0; c < 8; ++c) S1[c][h * DIMF + j] = acc[c];
        }
    }
    __syncthreads();

    // ---- C: logits + softmax -> S3 (wsm[c][h*32+k]) ----
    {
        int ni = nbrl[c8][k32];
        const float* nrow = feats + (long)(ni < 0 ? 0 : ni) * DIMF;
        float lg[4] = {0.f, 0.f, 0.f, 0.f};
        for (int jj = 0; jj < 32; ++jj) {
            float4 f = *(const float4*)&nrow[jj * 4];
#pragma unroll
            for (int h = 0; h < 4; ++h) {
                float4 qwv = *(const float4*)&S1[c8][h * DIMF + jj * 4];
                lg[h] += f.x * qwv.x + f.y * qwv.y + f.z * qwv.z + f.w * qwv.w;
            }
        }
        if (ni < 0) { lg[0] = -1e9f; lg[1] = -1e9f; lg[2] = -1e9f; lg[3] = -1e9f; }
#pragma unroll
        for (int h = 0; h < 4; ++h) {
            float mx = lg[h];
            for (int o = 16; o; o >>= 1) mx = fmaxf(mx, __shfl_xor(mx, o, 32));
            float e = expf(lg[h] - mx);
            float s = e;
            for (int o = 16; o; o >>= 1) s += __shfl_xor(s, o, 32);
            S3[c8][h * KNBR + k32] = e / s;
        }
    }
    __syncthreads();

    // ---- D: pool[c][h][j] = sum_k wsm * nf -> S1 (overwrite qw) ----
    {
        int j4 = k32 * 4;
        float a0x = 0.f, a0y = 0.f, a0z = 0.f, a0w = 0.f;
        float a1x = 0.f, a1y = 0.f, a1z = 0.f, a1w = 0.f;
        float a2x = 0.f, a2y = 0.f, a2z = 0.f, a2w = 0.f;
        float a3x = 0.f, a3y = 0.f, a3z = 0.f, a3w = 0.f;
        for (int k = 0; k < KNBR; ++k) {
            int ni = nbrl[c8][k];
            const float* nrow = feats + (long)(ni < 0 ? 0 : ni) * DIMF;
            float4 f = *(const float4*)&nrow[j4];
            float w0 = S3[c8][0 * KNBR + k], w1 = S3[c8][1 * KNBR + k];
            float w2 = S3[c8][2 * KNBR + k], w3 = S3[c8][3 * KNBR + k];
            a0x += w0 * f.x; a0y += w0 * f.y; a0z += w0 * f.z; a0w += w0 * f.w;
            a1x += w1 * f.x; a1y += w1 * f.y; a1z += w1 * f.z; a1w += w1 * f.w;
            a2x += w2 * f.x; a2y += w2 * f.y; a2z += w2 * f.z; a2w += w2 * f.w;
            a3x += w3 * f.x; a3y += w3 * f.y; a3z += w3 * f.z; a3w += w3 * f.w;
        }
        __syncthreads();
        *(float4*)&S1[c8][0 * DIMF + j4] = make_float4(a0x, a0y, a0z, a0w);
        *(float4*)&S1[c8][1 * DIMF + j4] = make_float4(a1x, a1y, a1z, a1w);
        *(float4*)&S1[c8][2 * DIMF + j4] = make_float4(a2x, a2y, a2z, a2w);
        *(float4*)&S1[c8][3 * DIMF + j4] = make_float4(a3x, a3y, a3z, a3w);
    }
    __syncthreads();

    // ---- E: updin[c][i->d*4+h] = Wv[i] . pool[c][h(i)] -> S2 ----
    {
        int i = lane127, h = i >> 5, d = i & 31;
        float acc[4] = {0.f, 0.f, 0.f, 0.f};
        for (int jj = 0; jj < 32; ++jj) {
            float w0 = WvT[(jj * 4 + 0) * DIMF + i];
            float w1 = WvT[(jj * 4 + 1) * DIMF + i];
            float w2 = WvT[(jj * 4 + 2) * DIMF + i];
            float w3 = WvT[(jj * 4 + 3) * DIMF + i];
#pragma unroll
            for (int cc = 0; cc < 4; ++cc) {
                float4 pv = *(const float4*)&S1[cg + cc][h * DIMF + jj * 4];
                acc[cc] += w0 * pv.x + w1 * pv.y + w2 * pv.z + w3 * pv.w;
            }
        }
        __syncthreads();
#pragma unroll
        for (int cc = 0; cc < 4; ++cc) S2[cg + cc][d * NH + h] = acc[cc];
    }
    __syncthreads();

    // ---- F: upd = Wo @ updin + bo -> S3 ----
    {
        int i = lane127;
        float acc[4] = {0.f, 0.f, 0.f, 0.f};
        for (int jj = 0; jj < 32; ++jj) {
            float w0 = WoT[(jj * 4 + 0) * DIMF + i];
            float w1 = WoT[(jj * 4 + 1) * DIMF + i];
            float w2 = WoT[(jj * 4 + 2) * DIMF + i];
            float w3 = WoT[(jj * 4 + 3) * DIMF + i];
#pragma unroll
            for (int cc = 0; cc < 4; ++cc) {
                float4 x = *(const float4*)&S2[cg + cc][jj * 4];
                acc[cc] += w0 * x.x + w1 * x.y + w2 * x.z + w3 * x.w;
            }
        }
        float b = bo[i];
        __syncthreads();
#pragma unroll
        for (int cc = 0; cc < 4; ++cc) S3[cg + cc][i] = acc[cc] + b;
    }
    __syncthreads();

    // ---- G: LN1 + residual -> cf2 ----
    {
        int i4 = k32 * 4;
        float4 u = *(const float4*)&S3[c8][i4];
        float s = ((u.x + u.y) + u.z) + u.w;
        for (int o = 16; o; o >>= 1) s += __shfl_xor(s, o, 32);
        float mu = s * (1.0f / DIMF);
        float d0 = u.x - mu, d1 = u.y - mu, d2 = u.z - mu, d3 = u.w - mu;
        float vs = ((d0 * d0 + d1 * d1) + d2 * d2) + d3 * d3;
        for (int o = 16; o; o >>= 1) vs += __shfl_xor(vs, o, 32);
        float rs = 1.0f / sqrtf(vs * (1.0f / DIMF) + 1e-5f);
        float4 g = *(const float4*)&g1[i4];
        float4 b = *(const float4*)&be1[i4];
        float4 base = *(const float4*)&cf[c8][i4];
        float4 r;
        r.x = base.x + d0 * rs * g.x + b.x;
        r.y = base.y + d1 * rs * g.y + b.y;
        r.z = base.z + d2 * rs * g.z + b.z;
        r.w = base.w + d3 * rs * g.w + b.w;
        *(float4*)&cf2[c8][i4] = r;
    }
    __syncthreads();

    // ---- H: FFN1 (relu(W1 @ cf2 + b1f)) -> S1 ----
    {
        int u0 = lane127;
        float acc[4][4];
#pragma unroll
        for (int p = 0; p < 4; ++p)
#pragma unroll
            for (int cc = 0; cc < 4; ++cc) acc[p][cc] = 0.f;
        for (int jj = 0; jj < 32; ++jj) {
            float4 x[4];
#pragma unroll
            for (int cc = 0; cc < 4; ++cc) x[cc] = *(const float4*)&cf2[cg + cc][jj * 4];
#pragma unroll
            for (int p = 0; p < 4; ++p) {
                int u = u0 + p * DIMF;
                float w0 = W1T[(long)(jj * 4 + 0) * (4 * DIMF) + u];
                float w1 = W1T[(long)(jj * 4 + 1) * (4 * DIMF) + u];
                float w2 = W1T[(long)(jj * 4 + 2) * (4 * DIMF) + u];
                float w3 = W1T[(long)(jj * 4 + 3) * (4 * DIMF) + u];
#pragma unroll
                for (int cc = 0; cc < 4; ++cc)
                    acc[p][cc] += w0 * x[cc].x + w1 * x[cc].y + w2 * x[cc].z + w3 * x[cc].w;
            }
        }
#pragma unroll
        for (int p = 0; p < 4; ++p) {
            float b = b1f[u0 + p * DIMF];
#pragma unroll
            for (int cc = 0; cc < 4; ++cc)
                S1[cg + cc][u0 + p * DIMF] = fmaxf(acc[p][cc] + b, 0.f);
        }
    }
    __syncthreads();

    // ---- I: FFN2 (W2 @ h1 + b2f) -> S3 ----
    {
        int i = lane127;
        float acc[4] = {0.f, 0.f, 0.f, 0.f};
        for (int uu = 0; uu < 128; ++uu) {
            float w0 = W2T[(long)(uu * 4 + 0) * DIMF + i];
            float w1 = W2T[(long)(uu * 4 + 1) * DIMF + i];
            float w2 = W2T[(long)(uu * 4 + 2) * DIMF + i];
            float w3 = W2T[(long)(uu * 4 + 3) * DIMF + i];
#pragma unroll
            for (int cc = 0; cc < 4; ++cc) {
                float4 hh = *(const float4*)&S1[cg + cc][uu * 4];
                acc[cc] += w0 * hh.x + w1 * hh.y + w2 * hh.z + w3 * hh.w;
            }
        }
        float b = b2f[i];
        __syncthreads();
#pragma unroll
        for (int cc = 0; cc < 4; ++cc) S3[cg + cc][i] = acc[cc] + b;
    }
    __syncthreads();

    // ---- J: LN2 + residual -> cfin ----
    {
        int i4 = k32 * 4;
        float4 u = *(const float4*)&S3[c8][i4];
        float s = ((u.x + u.y) + u.z) + u.w;
        for (int o = 16; o; o >>= 1) s += __shfl_xor(s, o, 32);
        float mu = s * (1.0f / DIMF);
        float d0 = u.x - mu, d1 = u.y - mu, d2 = u.z - mu, d3 = u.w - mu;
        float vs = ((d0 * d0 + d1 * d1) + d2 * d2) + d3 * d3;
        for (int o = 16; o; o >>= 1) vs += __shfl_xor(vs, o, 32);
        float rs = 1.0f / sqrtf(vs * (1.0f / DIMF) + 1e-5f);
        float4 g = *(const float4*)&g2[i4];
        float4 b = *(const float4*)&be2[i4];
        float4 base = *(const float4*)&cf2[c8][i4];
        float4 r;
        r.x = base.x + d0 * rs * g.x + b.x;
        r.y = base.y + d1 * rs * g.y + b.y;
        r.z = base.z + d2 * rs * g.z + b.z;
        r.w = base.w + d3 * rs * g.w + b.w;
        *(float4*)&cfin[(long)(m0 + c8) * DIMF + i4] = r;
    }
}

// ================= kernel 3: out = feats + cfin[bestm] ======================
__global__ __launch_bounds__(256) void out_kernel(const float4* __restrict__ feats4,
                                                  const float* __restrict__ cfin,
                                                  const int* __restrict__ bestm,
                                                  float4* __restrict__ out4, int total) {
    int idx = blockIdx.x * 256 + threadIdx.x;
    if (idx >= total) return;
    int n = idx >> 5, c = idx & 31;
    const float4* cf4 = (const float4*)cfin;
    float4 f = feats4[idx];
    float4 g = cf4[(long)bestm[n] * 32 + c];
    out4[idx] = make_float4(f.x + g.x, f.y + g.y, f.z + g.z, f.w + g.w);
}

extern "C" void kernel_launch(void* const* d_in, const int* in_sizes, int n_in,
                              void* d_out, int out_size, void* d_ws, size_t ws_size,
                              hipStream_t stream) {
    const float* xyz = (const float*)d_in[0];
    const float* feats = (const float*)d_in[1];
    const int* idxc = (const int*)d_in[2];
    const float* Wq = (const float*)d_in[3];
    const float* Wk = (const float*)d_in[4];
    const float* Wv = (const float*)d_in[5];
    const float* Wo = (const float*)d_in[6];
    const float* bo = (const float*)d_in[7];
    const float* g1 = (const float*)d_in[8];
    const float* be1 = (const float*)d_in[9];
    const float* g2 = (const float*)d_in[10];
    const float* be2 = (const float*)d_in[11];
    const float* W1 = (const float*)d_in[12];
    const float* b1f = (const float*)d_in[13];
    const float* W2 = (const float*)d_in[14];
    const float* b2f = (const float*)d_in[15];

    int N = in_sizes[0] / 3;
    int M = in_sizes[2];

    char* ws = (char*)d_ws;
    size_t off = 0;
    int* nbr = (int*)(ws + off); off += (size_t)M * KNBR * 4;
    float* cfin = (float*)(ws + off); off += (size_t)M * DIMF * 4;
    int* bestm = (int*)(ws + off); off += (size_t)N * 4;
    float* WqT = (float*)(ws + off); off += (size_t)DIMF * DIMF * 4;
    float* WvT = (float*)(ws + off); off += (size_t)DIMF * DIMF * 4;
    float* WoT = (float*)(ws + off); off += (size_t)DIMF * DIMF * 4;
    float* W1T = (float*)(ws + off); off += (size_t)4 * DIMF * DIMF * 4;
    float* W2T = (float*)(ws + off); off += (size_t)4 * DIMF * DIMF * 4;
    (void)ws_size; (void)n_in; (void)out_size;

    fused_front_kernel<<<FRONT_BLOCKS, 256, 0, stream>>>(
        xyz, idxc, Wq, Wv, Wo, W1, W2, WqT, WvT, WoT, W1T, W2T, nbr, bestm, N, M);
    attn_ffn_kernel<<<M / CB, 256, 0, stream>>>(feats, idxc, nbr, WqT, Wk, WvT, WoT, bo,
                                                g1, be1, g2, be2, W1T, b1f, W2T, b2f, cfin);
    out_kernel<<<(N * DIMF / 4 + 255) / 256, 256, 0, stream>>>(
        (const float4*)feats, cfin, bestm, (float4*)d_out, N * DIMF / 4);
}

// Round 7
// 215.516 us; speedup vs baseline: 1.2384x; 1.0394x over previous
//
#include <hip/hip_runtime.h>
#include <hip/hip_bf16.h>

#define DIMF 128
#define KNBR 32
#define NH 4
#define DH 32
#define RADIUS 0.3f
#define CB 8       // centers per attn block
#define TC 8       // centers per topk block (R7: was 4 — amortize point loads)
#define CAND 256   // max candidates/center (Poisson max lambda~118; 256 is ~12 sigma)
#define PPB 32     // points per nearest block

#define TOPK_BLOCKS 512    // M/TC
#define NEAR_BLOCKS 512    // N/PPB
#define PACK_BLOCKS 60     // 4+4+4+16+16 float4-transposes + 16 Wk-pack
#define FRONT_BLOCKS (TOPK_BLOCKS + NEAR_BLOCKS + PACK_BLOCKS)

typedef unsigned long long u64t;

// float4-granular transpose tile: out4[a*BI + b] = in4[b*AI + a]
__device__ __forceinline__ void tr4_tile(const float4* __restrict__ in4, float4* __restrict__ out4,
                                         int AI, int BI, int a0, int b0, int t, char* smem) {
    float4(*tile)[33] = (float4(*)[33])smem;
    int tx = t & 31, ty = t >> 5;  // 32 x 8
    for (int r = ty; r < 32; r += 8) tile[r][tx] = in4[(long)(b0 + r) * AI + a0 + tx];
    __syncthreads();
    for (int r = ty; r < 32; r += 8) out4[(long)(a0 + r) * BI + b0 + tx] = tile[tx][r];
}

// ================= kernel 1: fused front (topk + nearest-argmin + weight packs)
__global__ __launch_bounds__(256) void fused_front_kernel(
    const float* __restrict__ xyz, const int* __restrict__ idxc,
    const float* __restrict__ Wq, const float* __restrict__ Wv,
    const float* __restrict__ Wo, const float* __restrict__ W1,
    const float* __restrict__ W2, const float* __restrict__ Wk,
    float4* __restrict__ qp4, float4* __restrict__ vp4, float4* __restrict__ op4,
    float4* __restrict__ w1p4, float4* __restrict__ w2p4, float4* __restrict__ kp4,
    int* __restrict__ nbr, int* __restrict__ bestm, int N, int M) {
    __shared__ __align__(16) char smem[16896];
    int b = blockIdx.x, t = threadIdx.x;

    if (b < TOPK_BLOCKS) {
        // ---------- radius top-K, 8 centers/block ----------
        u64t(*cand)[CAND] = (u64t(*)[CAND])smem;
        int* cnt = (int*)(smem + TC * CAND * 8);
        int m0 = b * TC;
        if (t < TC) cnt[t] = 0;
        __syncthreads();
        float nx[TC], ny[TC], nz[TC], cw[TC];
#pragma unroll
        for (int tc = 0; tc < TC; ++tc) {
            int ic = idxc[m0 + tc];
            float cx = xyz[3 * ic], cy = xyz[3 * ic + 1], cz = xyz[3 * ic + 2];
            cw[tc] = (cx * cx + cy * cy) + cz * cz;
            nx[tc] = -2.0f * cx; ny[tc] = -2.0f * cy; nz[tc] = -2.0f * cz;
        }
        const float R2 = RADIUS * RADIUS;
        for (int n = t; n < N; n += 256) {
            float x = xyz[3 * n], y = xyz[3 * n + 1], z = xyz[3 * n + 2];
            float pw = (x * x + y * y) + z * z;
            float rhs = R2 - pw;  // s < rhs  <=>  s + pw < R2
#pragma unroll
            for (int tc = 0; tc < TC; ++tc) {
                float s = fmaf(nx[tc], x, fmaf(ny[tc], y, fmaf(nz[tc], z, cw[tc])));
                if (s < rhs) {
                    int pos = atomicAdd(&cnt[tc], 1);
                    if (pos < CAND)
                        cand[tc][pos] = (((u64t)__float_as_uint(fmaxf(s + pw, 0.0f))) << 32) | (unsigned)n;
                }
            }
        }
        __syncthreads();
        // wave w extracts centers w and w+4 (keys unique -> rank select)
        int w = t >> 6, lane = t & 63;
        for (int rep = 0; rep < 2; ++rep) {
            int cidx = w + rep * 4;
            int C = cnt[cidx] < CAND ? cnt[cidx] : CAND;
            const u64t* vc = cand[cidx];
            int* outp = nbr + (m0 + cidx) * KNBR;
            if (C <= 64) {
                u64t mykey = (lane < C) ? vc[lane] : ~0ull;
                int rank = 0;
                for (int j = 0; j < C; ++j) rank += (vc[j] < mykey) ? 1 : 0;
                if (lane < C && rank < KNBR) outp[rank] = (int)(mykey & 0xffffffffu);
                if (lane >= C && lane < KNBR) outp[lane] = -1;
            } else {
                u64t mykey[4];
                int myrank[4];
#pragma unroll
                for (int s = 0; s < 4; ++s) {
                    int i = s * 64 + lane;
                    mykey[s] = (i < C) ? vc[i] : ~0ull;
                    myrank[s] = 0;
                }
                for (int j = 0; j < C; ++j) {
                    u64t kj = vc[j];
#pragma unroll
                    for (int s = 0; s < 4; ++s) myrank[s] += (kj < mykey[s]) ? 1 : 0;
                }
#pragma unroll
                for (int s = 0; s < 4; ++s) {
                    int i = s * 64 + lane;
                    if (i < C && myrank[s] < KNBR) outp[myrank[s]] = (int)(mykey[s] & 0xffffffffu);
                }
            }
        }
    } else if (b < TOPK_BLOCKS + NEAR_BLOCKS) {
        // ---------- nearest-center argmin, 32 pts/block, 8 lanes/pt ----------
        // stride-8 interleave keeps LDS conflict-free; two independent min
        // chains per lane for ILP; u64 (dist,idx) combine only at the end.
        float4* cds = (float4*)smem;
        int nb = b - TOPK_BLOCKS;
        int pt = t >> 3, q = t & 7;
        int n = nb * PPB + pt;
        float px = xyz[3 * n], py = xyz[3 * n + 1], pz = xyz[3 * n + 2];
        float pw = (px * px + py * py) + pz * pz;
        float bd0 = INFINITY, bd1 = INFINITY;
        int bm0 = 0, bm1 = 0;
        for (int c0 = 0; c0 < M; c0 += 1024) {
            __syncthreads();
            for (int i = t; i < 1024; i += 256) {
                int ic = idxc[c0 + i];
                float cx = xyz[3 * ic], cy = xyz[3 * ic + 1], cz = xyz[3 * ic + 2];
                cds[i] = make_float4(cx, cy, cz, (cx * cx + cy * cy) + cz * cz);
            }
            __syncthreads();
#pragma unroll 4
            for (int i = 0; i < 64; ++i) {
                int ci0 = q + (2 * i) * 8, ci1 = q + (2 * i + 1) * 8;
                float4 ca = cds[ci0];
                float4 cb = cds[ci1];
                float da = ca.w + pw - 2.0f * (ca.x * px + ca.y * py + ca.z * pz);
                float db = cb.w + pw - 2.0f * (cb.x * px + cb.y * py + cb.z * pz);
                float dista = sqrtf(fmaxf(da, 1e-12f));  // ref tie semantics (np.argmin on dist)
                float distb = sqrtf(fmaxf(db, 1e-12f));
                if (dista < bd0) { bd0 = dista; bm0 = c0 + ci0; }
                if (distb < bd1) { bd1 = distb; bm1 = c0 + ci1; }
            }
        }
        u64t k0 = (((u64t)__float_as_uint(bd0)) << 32) | (unsigned)bm0;
        u64t k1 = (((u64t)__float_as_uint(bd1)) << 32) | (unsigned)bm1;
        u64t best = k0 < k1 ? k0 : k1;
#pragma unroll
        for (int o = 1; o < 8; o <<= 1) {
            u64t ob = __shfl_xor(best, o);
            if (ob < best) best = ob;
        }
        if (q == 0) bestm[n] = (int)(best & 0xffffffffu);
    } else {
        // ---------- weight packs (float4-quad layouts for the attn GEMMs) ----
        int pk = b - (TOPK_BLOCKS + NEAR_BLOCKS);
        if (pk < 4) {
            tr4_tile((const float4*)Wq, qp4, 32, 128, 0, pk * 32, t, smem);
        } else if (pk < 8) {
            tr4_tile((const float4*)Wv, vp4, 32, 128, 0, (pk - 4) * 32, t, smem);
        } else if (pk < 12) {
            tr4_tile((const float4*)Wo, op4, 32, 128, 0, (pk - 8) * 32, t, smem);
        } else if (pk < 28) {
            tr4_tile((const float4*)W1, w1p4, 32, 512, 0, (pk - 12) * 32, t, smem);
        } else if (pk < 44) {
            int i = pk - 28;
            tr4_tile((const float4*)W2, w2p4, 128, 128, (i >> 2) * 32, (i & 3) * 32, t, smem);
        } else {
            // Wk pack: kp4[q*128+j] = {Wk[(4q+r)*128+j]}_{r=0..3}
            int idx = (pk - 44) * 256 + t;
            int q = idx >> 7, j = idx & 127;
            float4 w;
            w.x = Wk[(long)(4 * q + 0) * DIMF + j];
            w.y = Wk[(long)(4 * q + 1) * DIMF + j];
            w.z = Wk[(long)(4 * q + 2) * DIMF + j];
            w.w = Wk[(long)(4 * q + 3) * DIMF + j];
            kp4[q * DIMF + j] = w;
        }
    }
}

// ================= kernel 2: attention + FFN, 8 centers / 256 threads =======
// R3 structure; weights now read as packed float4 (1 load per 4-wide K-step).
__global__ __launch_bounds__(256) void attn_ffn_kernel(
    const float* __restrict__ feats, const int* __restrict__ idxc,
    const int* __restrict__ nbr,
    const float4* __restrict__ qp4, const float4* __restrict__ kp4,
    const float4* __restrict__ vp4, const float4* __restrict__ op4,
    const float* __restrict__ bo, const float* __restrict__ g1,
    const float* __restrict__ be1, const float* __restrict__ g2,
    const float* __restrict__ be2, const float4* __restrict__ w1p4,
    const float* __restrict__ b1f, const float4* __restrict__ w2p4,
    const float* __restrict__ b2f, float* __restrict__ cfin) {
    __shared__ __align__(16) float cf[CB][DIMF];
    __shared__ __align__(16) float cf2[CB][DIMF];
    __shared__ __align__(16) float S1[CB][4 * DIMF];  // qw -> pool -> h1
    __shared__ __align__(16) float S2[CB][DIMF];      // q -> updin
    __shared__ __align__(16) float S3[CB][DIMF];      // wsm -> upd -> ffn
    __shared__ int nbrl[CB][KNBR];

    int t = threadIdx.x;
    int m0 = blockIdx.x * CB;
    int lane127 = t & 127;
    int cg = (t >> 7) * 4;  // wave-uniform center group {0..3} or {4..7}
    int c8 = t >> 5, k32 = t & 31;

    {
        int ic = idxc[m0 + c8];
        *(float4*)&cf[c8][k32 * 4] = *(const float4*)&feats[(long)ic * DIMF + k32 * 4];
        nbrl[c8][k32] = nbr[(m0 + c8) * KNBR + k32];
    }
    __syncthreads();

    // ---- A: q = Wq @ cf (scaled) -> S2 ----
    {
        float acc[4] = {0.f, 0.f, 0.f, 0.f};
        for (int jj = 0; jj < 32; ++jj) {
            float4 w = qp4[jj * DIMF + lane127];
#pragma unroll
            for (int cc = 0; cc < 4; ++cc) {
                float4 x = *(const float4*)&cf[cg + cc][jj * 4];
                acc[cc] += w.x * x.x + w.y * x.y + w.z * x.z + w.w * x.w;
            }
        }
#pragma unroll
        for (int cc = 0; cc < 4; ++cc) S2[cg + cc][lane127] = acc[cc] * 0.17677669529663687f;
    }
    __syncthreads();

    // ---- B: qw[c][h][j] = sum_d q[c][h*32+d] * Wk[(h*32+d)*128+j] -> S1 ----
    {
        int j = lane127, hs = t >> 7;
#pragma unroll
        for (int hh = 0; hh < 2; ++hh) {
            int h = hs * 2 + hh;
            float acc[8] = {0.f, 0.f, 0.f, 0.f, 0.f, 0.f, 0.f, 0.f};
            for (int d4 = 0; d4 < 8; ++d4) {
                float4 w = kp4[(h * 8 + d4) * DIMF + j];
#pragma unroll
                for (int c = 0; c < 8; ++c) {
                    float4 qv = *(const float4*)&S2[c][h * DH + d4 * 4];
                    acc[c] += qv.x * w.x + qv.y * w.y + qv.z * w.z + qv.w * w.w;
                }
            }
#pragma unroll
            for (int c = 0; c < 8; ++c) S1[c][h * DIMF + j] = acc[c];
        }
    }
    __syncthreads();

    // ---- C: logits + softmax -> S3 (wsm[c][h*32+k]) ----
    {
        int ni = nbrl[c8][k32];
        const float* nrow = feats + (long)(ni < 0 ? 0 : ni) * DIMF;
        float lg[4] = {0.f, 0.f, 0.f, 0.f};
        for (int jj = 0; jj < 32; ++jj) {
            float4 f = *(const float4*)&nrow[jj * 4];
#pragma unroll
            for (int h = 0; h < 4; ++h) {
                float4 qwv = *(const float4*)&S1[c8][h * DIMF + jj * 4];
                lg[h] += f.x * qwv.x + f.y * qwv.y + f.z * qwv.z + f.w * qwv.w;
            }
        }
        if (ni < 0) { lg[0] = -1e9f; lg[1] = -1e9f; lg[2] = -1e9f; lg[3] = -1e9f; }
#pragma unroll
        for (int h = 0; h < 4; ++h) {
            float mx = lg[h];
            for (int o = 16; o; o >>= 1) mx = fmaxf(mx, __shfl_xor(mx, o, 32));
            float e = expf(lg[h] - mx);
            float s = e;
            for (int o = 16; o; o >>= 1) s += __shfl_xor(s, o, 32);
            S3[c8][h * KNBR + k32] = e / s;
        }
    }
    __syncthreads();

    // ---- D: pool[c][h][j] = sum_k wsm * nf -> S1 (overwrite qw) ----
    {
        int j4 = k32 * 4;
        float a0x = 0.f, a0y = 0.f, a0z = 0.f, a0w = 0.f;
        float a1x = 0.f, a1y = 0.f, a1z = 0.f, a1w = 0.f;
        float a2x = 0.f, a2y = 0.f, a2z = 0.f, a2w = 0.f;
        float a3x = 0.f, a3y = 0.f, a3z = 0.f, a3w = 0.f;
        for (int k = 0; k < KNBR; ++k) {
            int ni = nbrl[c8][k];
            const float* nrow = feats + (long)(ni < 0 ? 0 : ni) * DIMF;
            float4 f = *(const float4*)&nrow[j4];
            float w0 = S3[c8][0 * KNBR + k], w1 = S3[c8][1 * KNBR + k];
            float w2 = S3[c8][2 * KNBR + k], w3 = S3[c8][3 * KNBR + k];
            a0x += w0 * f.x; a0y += w0 * f.y; a0z += w0 * f.z; a0w += w0 * f.w;
            a1x += w1 * f.x; a1y += w1 * f.y; a1z += w1 * f.z; a1w += w1 * f.w;
            a2x += w2 * f.x; a2y += w2 * f.y; a2z += w2 * f.z; a2w += w2 * f.w;
            a3x += w3 * f.x; a3y += w3 * f.y; a3z += w3 * f.z; a3w += w3 * f.w;
        }
        __syncthreads();
        *(float4*)&S1[c8][0 * DIMF + j4] = make_float4(a0x, a0y, a0z, a0w);
        *(float4*)&S1[c8][1 * DIMF + j4] = make_float4(a1x, a1y, a1z, a1w);
        *(float4*)&S1[c8][2 * DIMF + j4] = make_float4(a2x, a2y, a2z, a2w);
        *(float4*)&S1[c8][3 * DIMF + j4] = make_float4(a3x, a3y, a3z, a3w);
    }
    __syncthreads();

    // ---- E: updin[c][i->d*4+h] = Wv[i] . pool[c][h(i)] -> S2 ----
    {
        int i = lane127, h = i >> 5, d = i & 31;
        float acc[4] = {0.f, 0.f, 0.f, 0.f};
        for (int jj = 0; jj < 32; ++jj) {
            float4 w = vp4[jj * DIMF + i];
#pragma unroll
            for (int cc = 0; cc < 4; ++cc) {
                float4 pv = *(const float4*)&S1[cg + cc][h * DIMF + jj * 4];
                acc[cc] += w.x * pv.x + w.y * pv.y + w.z * pv.z + w.w * pv.w;
            }
        }
        __syncthreads();
#pragma unroll
        for (int cc = 0; cc < 4; ++cc) S2[cg + cc][d * NH + h] = acc[cc];
    }
    __syncthreads();

    // ---- F: upd = Wo @ updin + bo -> S3 ----
    {
        int i = lane127;
        float acc[4] = {0.f, 0.f, 0.f, 0.f};
        for (int jj = 0; jj < 32; ++jj) {
            float4 w = op4[jj * DIMF + i];
#pragma unroll
            for (int cc = 0; cc < 4; ++cc) {
                float4 x = *(const float4*)&S2[cg + cc][jj * 4];
                acc[cc] += w.x * x.x + w.y * x.y + w.z * x.z + w.w * x.w;
            }
        }
        float b = bo[i];
        __syncthreads();
#pragma unroll
        for (int cc = 0; cc < 4; ++cc) S3[cg + cc][i] = acc[cc] + b;
    }
    __syncthreads();

    // ---- G: LN1 + residual -> cf2 ----
    {
        int i4 = k32 * 4;
        float4 u = *(const float4*)&S3[c8][i4];
        float s = ((u.x + u.y) + u.z) + u.w;
        for (int o = 16; o; o >>= 1) s += __shfl_xor(s, o, 32);
        float mu = s * (1.0f / DIMF);
        float d0 = u.x - mu, d1 = u.y - mu, d2 = u.z - mu, d3 = u.w - mu;
        float vs = ((d0 * d0 + d1 * d1) + d2 * d2) + d3 * d3;
        for (int o = 16; o; o >>= 1) vs += __shfl_xor(vs, o, 32);
        float rs = 1.0f / sqrtf(vs * (1.0f / DIMF) + 1e-5f);
        float4 g = *(const float4*)&g1[i4];
        float4 b = *(const float4*)&be1[i4];
        float4 base = *(const float4*)&cf[c8][i4];
        float4 r;
        r.x = base.x + d0 * rs * g.x + b.x;
        r.y = base.y + d1 * rs * g.y + b.y;
        r.z = base.z + d2 * rs * g.z + b.z;
        r.w = base.w + d3 * rs * g.w + b.w;
        *(float4*)&cf2[c8][i4] = r;
    }
    __syncthreads();

    // ---- H: FFN1 (relu(W1 @ cf2 + b1f)) -> S1 ----
    {
        int u0 = lane127;
        float acc[4][4];
#pragma unroll
        for (int p = 0; p < 4; ++p)
#pragma unroll
            for (int cc = 0; cc < 4; ++cc) acc[p][cc] = 0.f;
        for (int jj = 0; jj < 32; ++jj) {
            float4 x[4];
#pragma unroll
            for (int cc = 0; cc < 4; ++cc) x[cc] = *(const float4*)&cf2[cg + cc][jj * 4];
#pragma unroll
            for (int p = 0; p < 4; ++p) {
                float4 w = w1p4[jj * 512 + u0 + p * DIMF];
#pragma unroll
                for (int cc = 0; cc < 4; ++cc)
                    acc[p][cc] += w.x * x[cc].x + w.y * x[cc].y + w.z * x[cc].z + w.w * x[cc].w;
            }
        }
#pragma unroll
        for (int p = 0; p < 4; ++p) {
            float b = b1f[u0 + p * DIMF];
#pragma unroll
            for (int cc = 0; cc < 4; ++cc)
                S1[cg + cc][u0 + p * DIMF] = fmaxf(acc[p][cc] + b, 0.f);
        }
    }
    __syncthreads();

    // ---- I: FFN2 (W2 @ h1 + b2f) -> S3 ----
    {
        int i = lane127;
        float acc[4] = {0.f, 0.f, 0.f, 0.f};
        for (int uu = 0; uu < 128; ++uu) {
            float4 w = w2p4[uu * DIMF + i];
#pragma unroll
            for (int cc = 0; cc < 4; ++cc) {
                float4 hh = *(const float4*)&S1[cg + cc][uu * 4];
                acc[cc] += w.x * hh.x + w.y * hh.y + w.z * hh.z + w.w * hh.w;
            }
        }
        float b = b2f[i];
        __syncthreads();
#pragma unroll
        for (int cc = 0; cc < 4; ++cc) S3[cg + cc][i] = acc[cc] + b;
    }
    __syncthreads();

    // ---- J: LN2 + residual -> cfin ----
    {
        int i4 = k32 * 4;
        float4 u = *(const float4*)&S3[c8][i4];
        float s = ((u.x + u.y) + u.z) + u.w;
        for (int o = 16; o; o >>= 1) s += __shfl_xor(s, o, 32);
        float mu = s * (1.0f / DIMF);
        float d0 = u.x - mu, d1 = u.y - mu, d2 = u.z - mu, d3 = u.w - mu;
        float vs = ((d0 * d0 + d1 * d1) + d2 * d2) + d3 * d3;
        for (int o = 16; o; o >>= 1) vs += __shfl_xor(vs, o, 32);
        float rs = 1.0f / sqrtf(vs * (1.0f / DIMF) + 1e-5f);
        float4 g = *(const float4*)&g2[i4];
        float4 b = *(const float4*)&be2[i4];
        float4 base = *(const float4*)&cf2[c8][i4];
        float4 r;
        r.x = base.x + d0 * rs * g.x + b.x;
        r.y = base.y + d1 * rs * g.y + b.y;
        r.z = base.z + d2 * rs * g.z + b.z;
        r.w = base.w + d3 * rs * g.w + b.w;
        *(float4*)&cfin[(long)(m0 + c8) * DIMF + i4] = r;
    }
}

// ================= kernel 3: out = feats + cfin[bestm] ======================
__global__ __launch_bounds__(256) void out_kernel(const float4* __restrict__ feats4,
                                                  const float* __restrict__ cfin,
                                                  const int* __restrict__ bestm,
                                                  float4* __restrict__ out4, int total) {
    int idx = blockIdx.x * 256 + threadIdx.x;
    if (idx >= total) return;
    int n = idx >> 5, c = idx & 31;
    const float4* cf4 = (const float4*)cfin;
    float4 f = feats4[idx];
    float4 g = cf4[(long)bestm[n] * 32 + c];
    out4[idx] = make_float4(f.x + g.x, f.y + g.y, f.z + g.z, f.w + g.w);
}

extern "C" void kernel_launch(void* const* d_in, const int* in_sizes, int n_in,
                              void* d_out, int out_size, void* d_ws, size_t ws_size,
                              hipStream_t stream) {
    const float* xyz = (const float*)d_in[0];
    const float* feats = (const float*)d_in[1];
    const int* idxc = (const int*)d_in[2];
    const float* Wq = (const float*)d_in[3];
    const float* Wk = (const float*)d_in[4];
    const float* Wv = (const float*)d_in[5];
    const float* Wo = (const float*)d_in[6];
    const float* bo = (const float*)d_in[7];
    const float* g1 = (const float*)d_in[8];
    const float* be1 = (const float*)d_in[9];
    const float* g2 = (const float*)d_in[10];
    const float* be2 = (const float*)d_in[11];
    const float* W1 = (const float*)d_in[12];
    const float* b1f = (const float*)d_in[13];
    const float* W2 = (const float*)d_in[14];
    const float* b2f = (const float*)d_in[15];

    int N = in_sizes[0] / 3;
    int M = in_sizes[2];

    char* ws = (char*)d_ws;
    size_t off = 0;
    int* nbr = (int*)(ws + off); off += (size_t)M * KNBR * 4;
    float* cfin = (float*)(ws + off); off += (size_t)M * DIMF * 4;
    int* bestm = (int*)(ws + off); off += (size_t)N * 4;
    float4* qp4 = (float4*)(ws + off); off += (size_t)DIMF * DIMF * 4;
    float4* vp4 = (float4*)(ws + off); off += (size_t)DIMF * DIMF * 4;
    float4* op4 = (float4*)(ws + off); off += (size_t)DIMF * DIMF * 4;
    float4* kp4 = (float4*)(ws + off); off += (size_t)DIMF * DIMF * 4;
    float4* w1p4 = (float4*)(ws + off); off += (size_t)4 * DIMF * DIMF * 4;
    float4* w2p4 = (float4*)(ws + off); off += (size_t)4 * DIMF * DIMF * 4;
    (void)ws_size; (void)n_in; (void)out_size;

    fused_front_kernel<<<FRONT_BLOCKS, 256, 0, stream>>>(
        xyz, idxc, Wq, Wv, Wo, W1, W2, Wk,
        qp4, vp4, op4, w1p4, w2p4, kp4, nbr, bestm, N, M);
    attn_ffn_kernel<<<M / CB, 256, 0, stream>>>(feats, idxc, nbr, qp4, kp4, vp4, op4, bo,
                                                g1, be1, g2, be2, w1p4, b1f, w2p4, b2f, cfin);
    out_kernel<<<(N * DIMF / 4 + 255) / 256, 256, 0, stream>>>(
        (const float4*)feats, cfin, bestm, (float4*)d_out, N * DIMF / 4);
}

// Round 8
// 210.060 us; speedup vs baseline: 1.2705x; 1.0260x over previous
//
#include <hip/hip_runtime.h>
#include <hip/hip_bf16.h>

#define DIMF 128
#define KNBR 32
#define NH 4
#define DH 32
#define RADIUS 0.3f
#define CB 8       // centers per main block (topk TC == attn CB == 8)
#define CAND 256   // max candidates/center (Poisson max lambda~118)
#define PPB 32     // points per nearest block

#define NEAR_BLOCKS 512    // N/PPB
#define PACK_BLOCKS 60     // 4+4+4+16+16 float4-transposes + 16 Wk-pack
#define PREP_BLOCKS (NEAR_BLOCKS + PACK_BLOCKS)

typedef unsigned long long u64t;

// float4-granular transpose tile: out4[a*BI + b] = in4[b*AI + a]
__device__ __forceinline__ void tr4_tile(const float4* __restrict__ in4, float4* __restrict__ out4,
                                         int AI, int BI, int a0, int b0, int t, char* smem) {
    float4(*tile)[33] = (float4(*)[33])smem;
    int tx = t & 31, ty = t >> 5;  // 32 x 8
    for (int r = ty; r < 32; r += 8) tile[r][tx] = in4[(long)(b0 + r) * AI + a0 + tx];
    __syncthreads();
    for (int r = ty; r < 32; r += 8) out4[(long)(a0 + r) * BI + b0 + tx] = tile[tx][r];
}

// ================= kernel 1: prep (nearest-argmin + weight packs) ===========
__global__ __launch_bounds__(256) void prep_kernel(
    const float* __restrict__ xyz, const int* __restrict__ idxc,
    const float* __restrict__ Wq, const float* __restrict__ Wv,
    const float* __restrict__ Wo, const float* __restrict__ W1,
    const float* __restrict__ W2, const float* __restrict__ Wk,
    float4* __restrict__ qp4, float4* __restrict__ vp4, float4* __restrict__ op4,
    float4* __restrict__ w1p4, float4* __restrict__ w2p4, float4* __restrict__ kp4,
    int* __restrict__ bestm, int N, int M) {
    __shared__ __align__(16) char smem[16896];
    int b = blockIdx.x, t = threadIdx.x;

    if (b < NEAR_BLOCKS) {
        // ---------- nearest-center argmin, 32 pts/block, 8 lanes/pt ----------
        // Key: s = |c|^2 - 2 c.p  (== d2 - |p|^2; same argmin ordering, no sqrt
        // needed since sqrt is monotone). Exact-duplicate centers give exactly
        // equal s -> lexicographic (s, index) min == np.argmin first-occurrence.
        // Staged as (-2cx,-2cy,-2cz,|c|^2); stride-8 interleave: conflict-free.
        float4* cds = (float4*)smem;
        int pt = t >> 3, q = t & 7;
        int n = b * PPB + pt;
        float px = xyz[3 * n], py = xyz[3 * n + 1], pz = xyz[3 * n + 2];
        float bd0 = INFINITY, bd1 = INFINITY;
        int bm0 = 0, bm1 = 0;
        for (int c0 = 0; c0 < M; c0 += 1024) {
            __syncthreads();
            for (int i = t; i < 1024; i += 256) {
                int ic = idxc[c0 + i];
                float cx = xyz[3 * ic], cy = xyz[3 * ic + 1], cz = xyz[3 * ic + 2];
                cds[i] = make_float4(-2.0f * cx, -2.0f * cy, -2.0f * cz,
                                     (cx * cx + cy * cy) + cz * cz);
            }
            __syncthreads();
#pragma unroll 8
            for (int i = 0; i < 64; ++i) {
                int ci0 = q + (2 * i) * 8, ci1 = q + (2 * i + 1) * 8;
                float4 ca = cds[ci0];
                float4 cb = cds[ci1];
                float sa = fmaf(ca.x, px, fmaf(ca.y, py, fmaf(ca.z, pz, ca.w)));
                float sb = fmaf(cb.x, px, fmaf(cb.y, py, fmaf(cb.z, pz, cb.w)));
                if (sa < bd0) { bd0 = sa; bm0 = c0 + ci0; }  // strict <: ascending scan keeps lowest idx
                if (sb < bd1) { bd1 = sb; bm1 = c0 + ci1; }
            }
        }
        if (bd1 < bd0 || (bd1 == bd0 && bm1 < bm0)) { bd0 = bd1; bm0 = bm1; }
#pragma unroll
        for (int o = 1; o < 8; o <<= 1) {
            float obd = __shfl_xor(bd0, o);
            int obm = __shfl_xor(bm0, o);
            if (obd < bd0 || (obd == bd0 && obm < bm0)) { bd0 = obd; bm0 = obm; }
        }
        if (q == 0) bestm[n] = bm0;
    } else {
        // ---------- weight packs (float4-quad layouts for the attn GEMMs) ----
        int pk = b - NEAR_BLOCKS;
        if (pk < 4) {
            tr4_tile((const float4*)Wq, qp4, 32, 128, 0, pk * 32, t, smem);
        } else if (pk < 8) {
            tr4_tile((const float4*)Wv, vp4, 32, 128, 0, (pk - 4) * 32, t, smem);
        } else if (pk < 12) {
            tr4_tile((const float4*)Wo, op4, 32, 128, 0, (pk - 8) * 32, t, smem);
        } else if (pk < 28) {
            tr4_tile((const float4*)W1, w1p4, 32, 512, 0, (pk - 12) * 32, t, smem);
        } else if (pk < 44) {
            int i = pk - 28;
            tr4_tile((const float4*)W2, w2p4, 128, 128, (i >> 2) * 32, (i & 3) * 32, t, smem);
        } else {
            // Wk pack: kp4[q*128+j] = {Wk[(4q+r)*128+j]}_{r=0..3}
            int idx = (pk - 44) * 256 + t;
            int q = idx >> 7, j = idx & 127;
            float4 w;
            w.x = Wk[(long)(4 * q + 0) * DIMF + j];
            w.y = Wk[(long)(4 * q + 1) * DIMF + j];
            w.z = Wk[(long)(4 * q + 2) * DIMF + j];
            w.w = Wk[(long)(4 * q + 3) * DIMF + j];
            kp4[q * DIMF + j] = w;
        }
    }
}

// ================= kernel 2: main — topk + attention + FFN, 8 centers/block =
// topk phase writes nbrl straight to LDS; attn phases (R7 structure) consume
// it without a global round-trip. LDS union: cand[8][256] (16 KB) overlays the
// attn buffers (32 KB); nbrl + cnt live outside the union.
__global__ __launch_bounds__(256) void main_kernel(
    const float* __restrict__ xyz, const float* __restrict__ feats,
    const int* __restrict__ idxc,
    const float4* __restrict__ qp4, const float4* __restrict__ kp4,
    const float4* __restrict__ vp4, const float4* __restrict__ op4,
    const float* __restrict__ bo, const float* __restrict__ g1,
    const float* __restrict__ be1, const float* __restrict__ g2,
    const float* __restrict__ be2, const float4* __restrict__ w1p4,
    const float* __restrict__ b1f, const float4* __restrict__ w2p4,
    const float* __restrict__ b2f, float* __restrict__ cfin, int N) {
    __shared__ __align__(16) char smem[32768];
    __shared__ int nbrl[CB][KNBR];
    __shared__ int cnt[CB];

    int t = threadIdx.x;
    int m0 = blockIdx.x * CB;

    // ======== phase 1: radius top-K for centers m0..m0+7 ========
    {
        u64t(*cand)[CAND] = (u64t(*)[CAND])smem;
        if (t < CB) cnt[t] = 0;
        __syncthreads();
        float nx[CB], ny[CB], nz[CB], cw[CB];
#pragma unroll
        for (int tc = 0; tc < CB; ++tc) {
            int ic = idxc[m0 + tc];
            float cx = xyz[3 * ic], cy = xyz[3 * ic + 1], cz = xyz[3 * ic + 2];
            cw[tc] = (cx * cx + cy * cy) + cz * cz;
            nx[tc] = -2.0f * cx; ny[tc] = -2.0f * cy; nz[tc] = -2.0f * cz;
        }
        const float R2 = RADIUS * RADIUS;
        for (int n = t; n < N; n += 256) {
            float x = xyz[3 * n], y = xyz[3 * n + 1], z = xyz[3 * n + 2];
            float pw = (x * x + y * y) + z * z;
            float rhs = R2 - pw;  // s < rhs  <=>  s + pw < R2
#pragma unroll
            for (int tc = 0; tc < CB; ++tc) {
                float s = fmaf(nx[tc], x, fmaf(ny[tc], y, fmaf(nz[tc], z, cw[tc])));
                if (s < rhs) {
                    int pos = atomicAdd(&cnt[tc], 1);
                    if (pos < CAND)
                        cand[tc][pos] = (((u64t)__float_as_uint(fmaxf(s + pw, 0.0f))) << 32) | (unsigned)n;
                }
            }
        }
        __syncthreads();
        // wave w extracts centers w and w+4 via rank-select into LDS nbrl
        int w = t >> 6, lane = t & 63;
        for (int rep = 0; rep < 2; ++rep) {
            int cidx = w + rep * 4;
            int C = cnt[cidx] < CAND ? cnt[cidx] : CAND;
            const u64t* vc = cand[cidx];
            if (C <= 64) {
                u64t mykey = (lane < C) ? vc[lane] : ~0ull;
                int rank = 0;
                for (int j = 0; j < C; ++j) rank += (vc[j] < mykey) ? 1 : 0;
                if (lane < C && rank < KNBR) nbrl[cidx][rank] = (int)(mykey & 0xffffffffu);
                if (lane >= C && lane < KNBR) nbrl[cidx][lane] = -1;
            } else {
                u64t mykey[4];
                int myrank[4];
#pragma unroll
                for (int s = 0; s < 4; ++s) {
                    int i = s * 64 + lane;
                    mykey[s] = (i < C) ? vc[i] : ~0ull;
                    myrank[s] = 0;
                }
                for (int j = 0; j < C; ++j) {
                    u64t kj = vc[j];
#pragma unroll
                    for (int s = 0; s < 4; ++s) myrank[s] += (kj < mykey[s]) ? 1 : 0;
                }
#pragma unroll
                for (int s = 0; s < 4; ++s) {
                    int i = s * 64 + lane;
                    if (i < C && myrank[s] < KNBR) nbrl[cidx][myrank[s]] = (int)(mykey[s] & 0xffffffffu);
                }
            }
        }
    }
    __syncthreads();  // cand reads done; smem becomes attn buffers

    // ======== phase 2: attention + FFN (R7 structure) ========
    float(*cf)[DIMF] = (float(*)[DIMF])smem;
    float(*cf2)[DIMF] = (float(*)[DIMF])(smem + 4096);
    float(*S1)[4 * DIMF] = (float(*)[4 * DIMF])(smem + 8192);
    float(*S2)[DIMF] = (float(*)[DIMF])(smem + 24576);
    float(*S3)[DIMF] = (float(*)[DIMF])(smem + 28672);

    int lane127 = t & 127;
    int cg = (t >> 7) * 4;
    int c8 = t >> 5, k32 = t & 31;

    {
        int ic = idxc[m0 + c8];
        *(float4*)&cf[c8][k32 * 4] = *(const float4*)&feats[(long)ic * DIMF + k32 * 4];
    }
    __syncthreads();

    // ---- A: q = Wq @ cf (scaled) -> S2 ----
    {
        float acc[4] = {0.f, 0.f, 0.f, 0.f};
        for (int jj = 0; jj < 32; ++jj) {
            float4 w = qp4[jj * DIMF + lane127];
#pragma unroll
            for (int cc = 0; cc < 4; ++cc) {
                float4 x = *(const float4*)&cf[cg + cc][jj * 4];
                acc[cc] += w.x * x.x + w.y * x.y + w.z * x.z + w.w * x.w;
            }
        }
#pragma unroll
        for (int cc = 0; cc < 4; ++cc) S2[cg + cc][lane127] = acc[cc] * 0.17677669529663687f;
    }
    __syncthreads();

    // ---- B: qw[c][h][j] -> S1 ----
    {
        int j = lane127, hs = t >> 7;
#pragma unroll
        for (int hh = 0; hh < 2; ++hh) {
            int h = hs * 2 + hh;
            float acc[8] = {0.f, 0.f, 0.f, 0.f, 0.f, 0.f, 0.f, 0.f};
            for (int d4 = 0; d4 < 8; ++d4) {
                float4 w = kp4[(h * 8 + d4) * DIMF + j];
#pragma unroll
                for (int c = 0; c < 8; ++c) {
                    float4 qv = *(const float4*)&S2[c][h * DH + d4 * 4];
                    acc[c] += qv.x * w.x + qv.y * w.y + qv.z * w.z + qv.w * w.w;
                }
            }
#pragma unroll
            for (int c = 0; c < 8; ++c) S1[c][h * DIMF + j] = acc[c];
        }
    }
    __syncthreads();

    // ---- C: logits + softmax -> S3 ----
    {
        int ni = nbrl[c8][k32];
        const float* nrow = feats + (long)(ni < 0 ? 0 : ni) * DIMF;
        float lg[4] = {0.f, 0.f, 0.f, 0.f};
        for (int jj = 0; jj < 32; ++jj) {
            float4 f = *(const float4*)&nrow[jj * 4];
#pragma unroll
            for (int h = 0; h < 4; ++h) {
                float4 qwv = *(const float4*)&S1[c8][h * DIMF + jj * 4];
                lg[h] += f.x * qwv.x + f.y * qwv.y + f.z * qwv.z + f.w * qwv.w;
            }
        }
        if (ni < 0) { lg[0] = -1e9f; lg[1] = -1e9f; lg[2] = -1e9f; lg[3] = -1e9f; }
#pragma unroll
        for (int h = 0; h < 4; ++h) {
            float mx = lg[h];
            for (int o = 16; o; o >>= 1) mx = fmaxf(mx, __shfl_xor(mx, o, 32));
            float e = expf(lg[h] - mx);
            float s = e;
            for (int o = 16; o; o >>= 1) s += __shfl_xor(s, o, 32);
            S3[c8][h * KNBR + k32] = e / s;
        }
    }
    __syncthreads();

    // ---- D: pool -> S1 (overwrite qw) ----
    {
        int j4 = k32 * 4;
        float a0x = 0.f, a0y = 0.f, a0z = 0.f, a0w = 0.f;
        float a1x = 0.f, a1y = 0.f, a1z = 0.f, a1w = 0.f;
        float a2x = 0.f, a2y = 0.f, a2z = 0.f, a2w = 0.f;
        float a3x = 0.f, a3y = 0.f, a3z = 0.f, a3w = 0.f;
        for (int k = 0; k < KNBR; ++k) {
            int ni = nbrl[c8][k];
            const float* nrow = feats + (long)(ni < 0 ? 0 : ni) * DIMF;
            float4 f = *(const float4*)&nrow[j4];
            float w0 = S3[c8][0 * KNBR + k], w1 = S3[c8][1 * KNBR + k];
            float w2 = S3[c8][2 * KNBR + k], w3 = S3[c8][3 * KNBR + k];
            a0x += w0 * f.x; a0y += w0 * f.y; a0z += w0 * f.z; a0w += w0 * f.w;
            a1x += w1 * f.x; a1y += w1 * f.y; a1z += w1 * f.z; a1w += w1 * f.w;
            a2x += w2 * f.x; a2y += w2 * f.y; a2z += w2 * f.z; a2w += w2 * f.w;
            a3x += w3 * f.x; a3y += w3 * f.y; a3z += w3 * f.z; a3w += w3 * f.w;
        }
        __syncthreads();
        *(float4*)&S1[c8][0 * DIMF + j4] = make_float4(a0x, a0y, a0z, a0w);
        *(float4*)&S1[c8][1 * DIMF + j4] = make_float4(a1x, a1y, a1z, a1w);
        *(float4*)&S1[c8][2 * DIMF + j4] = make_float4(a2x, a2y, a2z, a2w);
        *(float4*)&S1[c8][3 * DIMF + j4] = make_float4(a3x, a3y, a3z, a3w);
    }
    __syncthreads();

    // ---- E: updin -> S2 ----
    {
        int i = lane127, h = i >> 5, d = i & 31;
        float acc[4] = {0.f, 0.f, 0.f, 0.f};
        for (int jj = 0; jj < 32; ++jj) {
            float4 w = vp4[jj * DIMF + i];
#pragma unroll
            for (int cc = 0; cc < 4; ++cc) {
                float4 pv = *(const float4*)&S1[cg + cc][h * DIMF + jj * 4];
                acc[cc] += w.x * pv.x + w.y * pv.y + w.z * pv.z + w.w * pv.w;
            }
        }
        __syncthreads();
#pragma unroll
        for (int cc = 0; cc < 4; ++cc) S2[cg + cc][d * NH + h] = acc[cc];
    }
    __syncthreads();

    // ---- F: upd = Wo @ updin + bo -> S3 ----
    {
        int i = lane127;
        float acc[4] = {0.f, 0.f, 0.f, 0.f};
        for (int jj = 0; jj < 32; ++jj) {
            float4 w = op4[jj * DIMF + i];
#pragma unroll
            for (int cc = 0; cc < 4; ++cc) {
                float4 x = *(const float4*)&S2[cg + cc][jj * 4];
                acc[cc] += w.x * x.x + w.y * x.y + w.z * x.z + w.w * x.w;
            }
        }
        float b = bo[i];
        __syncthreads();
#pragma unroll
        for (int cc = 0; cc < 4; ++cc) S3[cg + cc][i] = acc[cc] + b;
    }
    __syncthreads();

    // ---- G: LN1 + residual -> cf2 ----
    {
        int i4 = k32 * 4;
        float4 u = *(const float4*)&S3[c8][i4];
        float s = ((u.x + u.y) + u.z) + u.w;
        for (int o = 16; o; o >>= 1) s += __shfl_xor(s, o, 32);
        float mu = s * (1.0f / DIMF);
        float d0 = u.x - mu, d1 = u.y - mu, d2 = u.z - mu, d3 = u.w - mu;
        float vs = ((d0 * d0 + d1 * d1) + d2 * d2) + d3 * d3;
        for (int o = 16; o; o >>= 1) vs += __shfl_xor(vs, o, 32);
        float rs = 1.0f / sqrtf(vs * (1.0f / DIMF) + 1e-5f);
        float4 g = *(const float4*)&g1[i4];
        float4 b = *(const float4*)&be1[i4];
        float4 base = *(const float4*)&cf[c8][i4];
        float4 r;
        r.x = base.x + d0 * rs * g.x + b.x;
        r.y = base.y + d1 * rs * g.y + b.y;
        r.z = base.z + d2 * rs * g.z + b.z;
        r.w = base.w + d3 * rs * g.w + b.w;
        *(float4*)&cf2[c8][i4] = r;
    }
    __syncthreads();

    // ---- H: FFN1 relu -> S1 ----
    {
        int u0 = lane127;
        float acc[4][4];
#pragma unroll
        for (int p = 0; p < 4; ++p)
#pragma unroll
            for (int cc = 0; cc < 4; ++cc) acc[p][cc] = 0.f;
        for (int jj = 0; jj < 32; ++jj) {
            float4 x[4];
#pragma unroll
            for (int cc = 0; cc < 4; ++cc) x[cc] = *(const float4*)&cf2[cg + cc][jj * 4];
#pragma unroll
            for (int p = 0; p < 4; ++p) {
                float4 w = w1p4[jj * 512 + u0 + p * DIMF];
#pragma unroll
                for (int cc = 0; cc < 4; ++cc)
                    acc[p][cc] += w.x * x[cc].x + w.y * x[cc].y + w.z * x[cc].z + w.w * x[cc].w;
            }
        }
#pragma unroll
        for (int p = 0; p < 4; ++p) {
            float b = b1f[u0 + p * DIMF];
#pragma unroll
            for (int cc = 0; cc < 4; ++cc)
                S1[cg + cc][u0 + p * DIMF] = fmaxf(acc[p][cc] + b, 0.f);
        }
    }
    __syncthreads();

    // ---- I: FFN2 -> S3 ----
    {
        int i = lane127;
        float acc[4] = {0.f, 0.f, 0.f, 0.f};
        for (int uu = 0; uu < 128; ++uu) {
            float4 w = w2p4[uu * DIMF + i];
#pragma unroll
            for (int cc = 0; cc < 4; ++cc) {
                float4 hh = *(const float4*)&S1[cg + cc][uu * 4];
                acc[cc] += w.x * hh.x + w.y * hh.y + w.z * hh.z + w.w * hh.w;
            }
        }
        float b = b2f[i];
        __syncthreads();
#pragma unroll
        for (int cc = 0; cc < 4; ++cc) S3[cg + cc][i] = acc[cc] + b;
    }
    __syncthreads();

    // ---- J: LN2 + residual -> cfin ----
    {
        int i4 = k32 * 4;
        float4 u = *(const float4*)&S3[c8][i4];
        float s = ((u.x + u.y) + u.z) + u.w;
        for (int o = 16; o; o >>= 1) s += __shfl_xor(s, o, 32);
        float mu = s * (1.0f / DIMF);
        float d0 = u.x - mu, d1 = u.y - mu, d2 = u.z - mu, d3 = u.w - mu;
        float vs = ((d0 * d0 + d1 * d1) + d2 * d2) + d3 * d3;
        for (int o = 16; o; o >>= 1) vs += __shfl_xor(vs, o, 32);
        float rs = 1.0f / sqrtf(vs * (1.0f / DIMF) + 1e-5f);
        float4 g = *(const float4*)&g2[i4];
        float4 b = *(const float4*)&be2[i4];
        float4 base = *(const float4*)&cf2[c8][i4];
        float4 r;
        r.x = base.x + d0 * rs * g.x + b.x;
        r.y = base.y + d1 * rs * g.y + b.y;
        r.z = base.z + d2 * rs * g.z + b.z;
        r.w = base.w + d3 * rs * g.w + b.w;
        *(float4*)&cfin[(long)(m0 + c8) * DIMF + i4] = r;
    }
}

// ================= kernel 3: out = feats + cfin[bestm] ======================
__global__ __launch_bounds__(256) void out_kernel(const float4* __restrict__ feats4,
                                                  const float* __restrict__ cfin,
                                                  const int* __restrict__ bestm,
                                                  float4* __restrict__ out4, int total) {
    int idx = blockIdx.x * 256 + threadIdx.x;
    if (idx >= total) return;
    int n = idx >> 5, c = idx & 31;
    const float4* cf4 = (const float4*)cfin;
    float4 f = feats4[idx];
    float4 g = cf4[(long)bestm[n] * 32 + c];
    out4[idx] = make_float4(f.x + g.x, f.y + g.y, f.z + g.z, f.w + g.w);
}

extern "C" void kernel_launch(void* const* d_in, const int* in_sizes, int n_in,
                              void* d_out, int out_size, void* d_ws, size_t ws_size,
                              hipStream_t stream) {
    const float* xyz = (const float*)d_in[0];
    const float* feats = (const float*)d_in[1];
    const int* idxc = (const int*)d_in[2];
    const float* Wq = (const float*)d_in[3];
    const float* Wk = (const float*)d_in[4];
    const float* Wv = (const float*)d_in[5];
    const float* Wo = (const float*)d_in[6];
    const float* bo = (const float*)d_in[7];
    const float* g1 = (const float*)d_in[8];
    const float* be1 = (const float*)d_in[9];
    const float* g2 = (const float*)d_in[10];
    const float* be2 = (const float*)d_in[11];
    const float* W1 = (const float*)d_in[12];
    const float* b1f = (const float*)d_in[13];
    const float* W2 = (const float*)d_in[14];
    const float* b2f = (const float*)d_in[15];

    int N = in_sizes[0] / 3;
    int M = in_sizes[2];

    char* ws = (char*)d_ws;
    size_t off = 0;
    float* cfin = (float*)(ws + off); off += (size_t)M * DIMF * 4;
    int* bestm = (int*)(ws + off); off += (size_t)N * 4;
    float4* qp4 = (float4*)(ws + off); off += (size_t)DIMF * DIMF * 4;
    float4* vp4 = (float4*)(ws + off); off += (size_t)DIMF * DIMF * 4;
    float4* op4 = (float4*)(ws + off); off += (size_t)DIMF * DIMF * 4;
    float4* kp4 = (float4*)(ws + off); off += (size_t)DIMF * DIMF * 4;
    float4* w1p4 = (float4*)(ws + off); off += (size_t)4 * DIMF * DIMF * 4;
    float4* w2p4 = (float4*)(ws + off); off += (size_t)4 * DIMF * DIMF * 4;
    (void)ws_size; (void)n_in; (void)out_size;

    prep_kernel<<<PREP_BLOCKS, 256, 0, stream>>>(
        xyz, idxc, Wq, Wv, Wo, W1, W2, Wk,
        qp4, vp4, op4, w1p4, w2p4, kp4, bestm, N, M);
    main_kernel<<<M / CB, 256, 0, stream>>>(
        xyz, feats, idxc, qp4, kp4, vp4, op4, bo, g1, be1, g2, be2,
        w1p4, b1f, w2p4, b2f, cfin, N);
    out_kernel<<<(N * DIMF / 4 + 255) / 256, 256, 0, stream>>>(
        (const float4*)feats, cfin, bestm, (float4*)d_out, N * DIMF / 4);
}